// Round 11
// baseline (1856.582 us; speedup 1.0000x reference)
//
#include <hip/hip_runtime.h>
#include <cstdint>

static constexpr int B   = 8;
static constexpr int N0  = 4096;
static constexpr int NQ  = 1024;
static constexpr int KNB = 16;

// ---------------------------------------------------------------------------
// u64 wave max; result valid in LANE 63 only. No readlane/ballot — pure VALU.
// ---------------------------------------------------------------------------
__device__ __forceinline__ unsigned long long wave_max_u64_l63(unsigned long long k) {
#define STEPU_(ctrl)                                                                    \
  {                                                                                     \
    unsigned lo_ = (unsigned)k, hi_ = (unsigned)(k >> 32);                              \
    unsigned plo_ = (unsigned)__builtin_amdgcn_update_dpp((int)lo_, (int)lo_, ctrl,     \
                                                          0xf, 0xf, false);             \
    unsigned phi_ = (unsigned)__builtin_amdgcn_update_dpp((int)hi_, (int)hi_, ctrl,     \
                                                          0xf, 0xf, false);             \
    unsigned long long pk_ = ((unsigned long long)phi_ << 32) | plo_;                   \
    if (pk_ > k) k = pk_;                                                               \
  }
  STEPU_(0x111) STEPU_(0x112) STEPU_(0x114) STEPU_(0x118) STEPU_(0x142) STEPU_(0x143)
#undef STEPU_
  return k;
}

// ---------------------------------------------------------------------------
// gn inline formula — EXACT same expression as gn_out_kernel (bit-identical).
// ---------------------------------------------------------------------------
__device__ __forceinline__ float gnf(float mx, float mn, float scv, float mo, float gb) {
  float sel = (scv >= 0.f) ? mx : mn;
  float v = (sel - mo) * scv + gb;
  return (v > 0.f) ? v : 0.2f * v;
}

// ---------------------------------------------------------------------------
// prep: split x; write packed c4 = {x,y,z,|c|^2}, normal, plane, f0, AND
// ctrY1 (layer-1 center projection) — same fmaf order as the old ctry body.
// ---------------------------------------------------------------------------
__global__ void prep_kernel(const float* __restrict__ x,
                            const float* __restrict__ W_in,
                            const float* __restrict__ b_in,
                            const float* __restrict__ W1,
                            float4* __restrict__ c4, float* __restrict__ nrm,
                            float* __restrict__ pl, float* __restrict__ f0,
                            float* __restrict__ ctrY1) {
  int i = blockIdx.x * 256 + threadIdx.x;
  if (i >= B * N0) return;
  const float* xp = x + (size_t)i * 7;
  float cx = xp[0], cy = xp[1], cz = xp[2];
  // tie-sensitive (feeds kNN distance): exact fp32, ref association order
  float kk = __fadd_rn(__fadd_rn(__fmul_rn(cx, cx), __fmul_rn(cy, cy)), __fmul_rn(cz, cz));
  c4[i] = make_float4(cx, cy, cz, kk);
  nrm[i * 3 + 0] = xp[3]; nrm[i * 3 + 1] = xp[4]; nrm[i * 3 + 2] = xp[5];
  pl[i] = xp[6];
  float f[8];
#pragma unroll
  for (int o = 0; o < 8; o++) {
    f[o] = cx * W_in[o * 3 + 0] + cy * W_in[o * 3 + 1] + cz * W_in[o * 3 + 2] + b_in[o];
    f0[(size_t)i * 8 + o] = f[o];
  }
#pragma unroll
  for (int o = 0; o < 32; o++) {
    const float* wp = W1 + (size_t)o * 16 + 8;
    float acc = 0.f;
#pragma unroll
    for (int c = 0; c < 8; c++) acc = fmaf(f[c], wp[c], acc);
    ctrY1[(size_t)i * 32 + o] = acc;
  }
}

// ---------------------------------------------------------------------------
// kNN body: STREAMING INSERTION TOP-K (harness-verified). Wave per query.
// ---------------------------------------------------------------------------
template <int NC>
__device__ __forceinline__ void knn_body(int bq, int lane,
                                         const float4* __restrict__ q4,
                                         const float4* __restrict__ k4,
                                         int Q, int Nk, int* __restrict__ out) {
  int b = bq / Q;
  float4 q = q4[bq];
  const float4* kb = k4 + (size_t)b * Nk + lane;
  const float INF    = __int_as_float(0x7f800000);
  const float NEGINF = __int_as_float(0xff800000);
  float myd = INF;
  int   myi = 0;
  float kth = INF;
  const bool isl0 = (lane & 15) == 0;
  constexpr int G = (NC >= 8) ? 8 : NC;
  for (int c0 = 0; c0 < NC; c0 += G) {
    float dg[G];
#pragma unroll
    for (int u = 0; u < G; u++) {
      float4 kp = kb[(c0 + u) * 64];
      float dot = __fadd_rn(__fadd_rn(__fmul_rn(q.x, kp.x), __fmul_rn(q.y, kp.y)),
                            __fmul_rn(q.z, kp.z));
      dg[u] = __fadd_rn(__fsub_rn(q.w, __fmul_rn(2.0f, dot)), kp.w);
    }
#pragma unroll
    for (int u = 0; u < G; u++) {
      float d = dg[u];
      unsigned long long msk = __ballot(d < kth);
      while (msk) {
        int j = __builtin_ctzll(msk);
        float dv = __int_as_float(__builtin_amdgcn_readlane(__float_as_int(d), j));
        int   iv = (c0 + u) * 64 + j;
        bool gt = (myd > dv);
        float pd = __int_as_float(__builtin_amdgcn_update_dpp(
            0, __float_as_int(myd), 0x111, 0xf, 0xf, true));
        int   pi = __builtin_amdgcn_update_dpp(0, myi, 0x111, 0xf, 0xf, true);
        pd = isl0 ? NEGINF : pd;
        bool tp = (pd > dv);
        float nd = tp ? pd : dv;
        int   ni = tp ? pi : iv;
        myd = gt ? nd : myd;
        myi = gt ? ni : myi;
        kth = __int_as_float(__builtin_amdgcn_readlane(__float_as_int(myd), 15));
        msk = __ballot(d < kth);
        msk = (j < 63) ? (msk & (~0ull << (j + 1))) : 0ull;
      }
    }
  }
  if (lane < KNB) out[(size_t)bq * KNB + lane] = myi;
}

// ---------------------------------------------------------------------------
// FPS v5 (harness-verified): BLK=256 (4 waves), one block per batch.
// (setprio removed — R10 A/B showed null.)
// ---------------------------------------------------------------------------
template <int NPTS>
__device__ __forceinline__ void fps_body(const float4* __restrict__ cb, int* w) {
  constexpr int BLK = 256;
  constexpr int M = NPTS / BLK;
  constexpr int NW = BLK / 64;  // 4
  __shared__ __align__(16) float2 sxy[NPTS];
  __shared__ float szz[NPTS];
  __shared__ __align__(16) unsigned long long skey[2][NW];
  const int tid = threadIdx.x;
  const int wid = tid >> 6, lane = tid & 63;
  float cx[M], cy[M], cz[M], dist[M];
#pragma unroll
  for (int i = 0; i < M; i++) {
    float4 p = cb[tid * M + i];
    cx[i] = p.x; cy[i] = p.y; cz[i] = p.z;
    dist[i] = 3.4e38f;
    sxy[tid * M + i] = make_float2(p.x, p.y);
    szz[tid * M + i] = p.z;
  }
  w[0] = w[1] = w[2] = w[3] = 0;
  float4 p0 = cb[0];
  float px = p0.x, py = p0.y, pz = p0.z;
  __syncthreads();
  for (int t = 1; t < NQ; t++) {
    float bv = -1.f; int bi = 0;
#pragma unroll
    for (int i = 0; i < M; i++) {
      float dx = __fsub_rn(cx[i], px), dy = __fsub_rn(cy[i], py), dz = __fsub_rn(cz[i], pz);
      float d = __fadd_rn(__fadd_rn(__fmul_rn(dx, dx), __fmul_rn(dy, dy)), __fmul_rn(dz, dz));
      float dd = dist[i]; dd = (d < dd) ? d : dd; dist[i] = dd;
      if (dd > bv) { bv = dd; bi = tid * M + i; }
    }
    unsigned long long k =
        ((unsigned long long)__float_as_uint(bv) << 12) | (unsigned)(4095 - bi);
    k = wave_max_u64_l63(k);
    int p = t & 1;
    if (lane == 63) skey[p][wid] = k;
    __syncthreads();
    ulonglong2 ab = *(const ulonglong2*)&skey[p][0];
    ulonglong2 cd = *(const ulonglong2*)&skey[p][2];
    unsigned long long m0 = (ab.x > ab.y) ? ab.x : ab.y;
    unsigned long long m1 = (cd.x > cd.y) ? cd.x : cd.y;
    unsigned long long mk = (m0 > m1) ? m0 : m1;
    int win = 4095 - (int)(mk & 0xFFFull);
    float2 pxy = sxy[win];
    px = pxy.x; py = pxy.y; pz = szz[win];
    if (t == tid) w[0] = win;
    if (t == tid + 256) w[1] = win;
    if (t == tid + 512) w[2] = win;
    if (t == tid + 768) w[3] = win;
  }
}

// ---------------------------------------------------------------------------
// FPS v10: SINGLE-WAVE fps for NPTS=1024 (M=16/lane), REGISTER-ONLY reduce.
// Zero cross-wave traffic: no barrier, no LDS on the serial chain. Per-lane
// scan tracks (bv, bi, bx, by, bz); coord cndmasks hang OFF the compare
// chain. Wave phase: 6 DPP v_max_f32 (lane63 valid) -> readlane -> ballot
// (bv==wmax) -> ctz -> owner lane L -> 4 readlanes (win, x, y, z).
// Tie semantics: lane-major ownership => (max d, min lane, min i) == min
// global index among maxima == jnp.argmax first-occurrence == the
// harness-verified v5 key order. Winners stream to swin (lane-0 ds_write,
// never waited on in-loop); same-wave gather reads them after the loop.
// ---------------------------------------------------------------------------
template <int NPTS>
__device__ __forceinline__ void fps1w_body(const float4* __restrict__ cb,
                                           int* __restrict__ swin) {
  constexpr int M = NPTS / 64;  // 16
  const int lane = threadIdx.x;  // caller guarantees threadIdx.x < 64
  float cx[M], cy[M], cz[M], dist[M];
#pragma unroll
  for (int i = 0; i < M; i++) {
    float4 p = cb[lane * M + i];
    cx[i] = p.x; cy[i] = p.y; cz[i] = p.z;
    dist[i] = 3.4e38f;
  }
  float4 p0 = cb[0];
  float px = p0.x, py = p0.y, pz = p0.z;
  for (int t = 1; t < NQ; t++) {
    float bv = -1.f; int bi = 0;
    float bx = px, by = py, bz = pz;  // dd >= 0 > -1 so always overwritten
#pragma unroll
    for (int i = 0; i < M; i++) {
      float dx = __fsub_rn(cx[i], px), dy = __fsub_rn(cy[i], py), dz = __fsub_rn(cz[i], pz);
      float d = __fadd_rn(__fadd_rn(__fmul_rn(dx, dx), __fmul_rn(dy, dy)), __fmul_rn(dz, dz));
      float dd = dist[i]; dd = (d < dd) ? d : dd; dist[i] = dd;
      if (dd > bv) { bv = dd; bi = lane * M + i; bx = cx[i]; by = cy[i]; bz = cz[i]; }
    }
    float wm = bv;
#define SMAX_(ctrl)                                                                     \
  {                                                                                     \
    int t_ = __builtin_amdgcn_update_dpp(__float_as_int(wm), __float_as_int(wm), ctrl,  \
                                         0xf, 0xf, false);                              \
    wm = fmaxf(wm, __int_as_float(t_));                                                 \
  }
    SMAX_(0x111) SMAX_(0x112) SMAX_(0x114) SMAX_(0x118) SMAX_(0x142) SMAX_(0x143)
#undef SMAX_
    float wmax = __int_as_float(__builtin_amdgcn_readlane(__float_as_int(wm), 63));
    unsigned long long tied = __ballot(bv == wmax);
    int L = (int)__builtin_ctzll(tied);  // min lane == min global index
    int win = __builtin_amdgcn_readlane(bi, L);
    px = __int_as_float(__builtin_amdgcn_readlane(__float_as_int(bx), L));
    py = __int_as_float(__builtin_amdgcn_readlane(__float_as_int(by), L));
    pz = __int_as_float(__builtin_amdgcn_readlane(__float_as_int(bz), L));
    if (lane == 0) swin[t] = win;
  }
}

// ---------------------------------------------------------------------------
// FUSED kNN + edge-conv body (layer 1; f0/ctrY1 materialized). Verbatim R8.
// ---------------------------------------------------------------------------
template <int NC, int CF, int CO>
__device__ __forceinline__ void knnec_body(
    int blkid, const float4* __restrict__ q4, const float4* __restrict__ k4,
    const float* __restrict__ fq, const float* __restrict__ fk,
    const float* __restrict__ Wfull, const float* __restrict__ ctrY,
    const int* __restrict__ ridx,
    float* __restrict__ ymin, float* __restrict__ ymax,
    float* __restrict__ gstats, int Q, int Nk) {
  constexpr int J = CO / 4;
  constexpr int SEC = J * CF + 8;
  __shared__ float Wl[4 * SEC];
  __shared__ float sstat[8];
  for (int t = threadIdx.x; t < CO * CF; t += 256) {
    int o = t / CF, c = t % CF;
    Wl[(o / J) * SEC + (o % J) * CF + c] = Wfull[(size_t)o * (2 * CF) + c];
  }
  if (threadIdx.x < 8) sstat[threadIdx.x] = 0.0f;
  __syncthreads();
  const int wid = threadIdx.x >> 6, lane = threadIdx.x & 63;
  const int bq = blkid * 4 + wid;
  const int b = bq / Q;
  // kNN phase
  float4 q = q4[bq];
  const float4* kb = k4 + (size_t)b * Nk + lane;
  const float INF    = __int_as_float(0x7f800000);
  const float NEGINF = __int_as_float(0xff800000);
  float myd = INF;
  int   myi = 0;
  float kth = INF;
  const bool isl0 = (lane & 15) == 0;
  constexpr int G = (NC >= 8) ? 8 : NC;
  for (int c0 = 0; c0 < NC; c0 += G) {
    float dg[G];
#pragma unroll
    for (int u = 0; u < G; u++) {
      float4 kp = kb[(c0 + u) * 64];
      float dot = __fadd_rn(__fadd_rn(__fmul_rn(q.x, kp.x), __fmul_rn(q.y, kp.y)),
                            __fmul_rn(q.z, kp.z));
      dg[u] = __fadd_rn(__fsub_rn(q.w, __fmul_rn(2.0f, dot)), kp.w);
    }
#pragma unroll
    for (int u = 0; u < G; u++) {
      float d = dg[u];
      unsigned long long msk = __ballot(d < kth);
      while (msk) {
        int j = __builtin_ctzll(msk);
        float dv = __int_as_float(__builtin_amdgcn_readlane(__float_as_int(d), j));
        int   iv = (c0 + u) * 64 + j;
        bool gt = (myd > dv);
        float pd = __int_as_float(__builtin_amdgcn_update_dpp(
            0, __float_as_int(myd), 0x111, 0xf, 0xf, true));
        int   pi = __builtin_amdgcn_update_dpp(0, myi, 0x111, 0xf, 0xf, true);
        pd = isl0 ? NEGINF : pd;
        bool tp = (pd > dv);
        float nd = tp ? pd : dv;
        int   nI = tp ? pi : iv;
        myd = gt ? nd : myd;
        myi = gt ? nI : myi;
        kth = __int_as_float(__builtin_amdgcn_readlane(__float_as_int(myd), 15));
        msk = __ballot(d < kth);
        msk = (j < 63) ? (msk & (~0ull << (j + 1))) : 0ull;
      }
    }
  }
  // edge-conv phase
  const int g = lane >> 4;
  const int ni = myi;
  const float* nbp = fk + (size_t)(b * Nk + ni) * CF;
  const float* cp = ridx ? fq + ((size_t)b * Nk + ridx[bq]) * CF
                         : fq + (size_t)bq * CF;
  float acc[J];
#pragma unroll
  for (int j = 0; j < J; j++) acc[j] = 0.0f;
  const float* wg = &Wl[g * SEC];
#pragma unroll
  for (int c = 0; c < CF; c += 4) {
    float4 nb4 = *(const float4*)(nbp + c);
    float4 c4  = *(const float4*)(cp + c);
    float e0 = nb4.x - c4.x, e1 = nb4.y - c4.y, e2 = nb4.z - c4.z, e3 = nb4.w - c4.w;
#pragma unroll
    for (int j = 0; j < J; j++) {
      float4 w4 = *(const float4*)(wg + j * CF + c);
      acc[j] = fmaf(e0, w4.x, acc[j]);
      acc[j] = fmaf(e1, w4.y, acc[j]);
      acc[j] = fmaf(e2, w4.z, acc[j]);
      acc[j] = fmaf(e3, w4.w, acc[j]);
    }
  }
  float s = 0.f, s2 = 0.f;
  const float* cyp = ctrY + (size_t)bq * CO + g * J;
#pragma unroll
  for (int j = 0; j < J; j++) {
    float y = acc[j] + cyp[j];
    acc[j] = y;
    s += y; s2 = fmaf(y, y, s2);
  }
  float mn[J];
#pragma unroll
  for (int j = 0; j < J; j++) mn[j] = acc[j];
#pragma unroll
  for (int m = 1; m < 16; m <<= 1) {
#pragma unroll
    for (int j = 0; j < J; j++) {
      float a = __shfl_xor(acc[j], m); if (a > acc[j]) acc[j] = a;
      float c2 = __shfl_xor(mn[j], m); if (c2 < mn[j]) mn[j] = c2;
    }
    s  += __shfl_xor(s, m);
    s2 += __shfl_xor(s2, m);
  }
  if ((lane & 15) == 0) {
    float* mnp = ymin + (size_t)bq * CO + g * J;
    float* mxp = ymax + (size_t)bq * CO + g * J;
#pragma unroll
    for (int j = 0; j < J; j++) { mnp[j] = mn[j]; mxp[j] = acc[j]; }
    atomicAdd(&sstat[g], s);
    atomicAdd(&sstat[4 + g], s2);
  }
  __syncthreads();
  if (threadIdx.x < 8) atomicAdd(&gstats[b * 8 + threadIdx.x], sstat[threadIdx.x]);
}

// ---------------------------------------------------------------------------
// INLINE-GN edge-conv core (layers 2-4). Verbatim R9.
// ---------------------------------------------------------------------------
template <int NC, int CF, int CO, bool HAS_KNN>
__device__ __forceinline__ void ec_gn_core(
    int blkid, const float4* __restrict__ q4, const float4* __restrict__ k4,
    const int* __restrict__ knn,
    const float* __restrict__ yminP, const float* __restrict__ ymaxP,
    const float* __restrict__ gstP, const float* __restrict__ gwP,
    const float* __restrict__ gbP, float invP,
    const float* __restrict__ Wfull, const int* __restrict__ ridx,
    float* __restrict__ ymin, float* __restrict__ ymax,
    float* __restrict__ gstats, int Q, int Nk) {
  constexpr int J = CO / 4;
  constexpr int SEC = J * CF + 8;
  __shared__ float Wl[4 * SEC];
  __shared__ float sstat[8];
  __shared__ __align__(16) float t_scv[CF];
  __shared__ __align__(16) float t_mo[CF];
  __shared__ __align__(16) float t_gb[CF];
  __shared__ __align__(16) float wfc[4][CF];
  __shared__ float scy[4][CO];
  const int b = (blkid * 4) / Q;  // block-uniform (Q % 4 == 0)
  for (int t = threadIdx.x; t < CO * CF; t += 256) {
    int o = t / CF, c = t % CF;
    Wl[(o / J) * SEC + (o % J) * CF + c] = Wfull[(size_t)o * (2 * CF) + c];
  }
  if (threadIdx.x < CF) {
    int c = threadIdx.x;
    int gg = c / (CF / 4);
    float m  = gstP[b * 8 + gg] * invP;
    float s2 = gstP[b * 8 + 4 + gg] * invP;
    float rs = rsqrtf(s2 - m * m + 1e-5f);
    t_scv[c] = gwP[c] * rs;
    t_mo[c]  = m;
    t_gb[c]  = gbP[c];
  }
  if (threadIdx.x < 8) sstat[threadIdx.x] = 0.0f;
  __syncthreads();
  const int wid = threadIdx.x >> 6, lane = threadIdx.x & 63;
  const int bq = blkid * 4 + wid;
  // center f row (inline-gn), then this-layer ctrY row (in-wave dot)
  size_t cbase = (ridx ? ((size_t)b * Nk + ridx[bq]) : (size_t)bq) * CF;
  if (lane < CF)
    wfc[wid][lane] = gnf(ymaxP[cbase + lane], yminP[cbase + lane],
                         t_scv[lane], t_mo[lane], t_gb[lane]);
  for (int oo = lane; oo < CO; oo += 64) {
    const float* wp = Wfull + (size_t)oo * (2 * CF) + CF;
    float acc0 = 0.f;
#pragma unroll
    for (int c = 0; c < CF; c++) acc0 = fmaf(wfc[wid][c], wp[c], acc0);
    scy[wid][oo] = acc0;
  }
  // neighbor index
  int ni;
  if (HAS_KNN) {
    float4 q = q4[bq];
    const float4* kb = k4 + (size_t)b * Nk + lane;
    const float INF    = __int_as_float(0x7f800000);
    const float NEGINF = __int_as_float(0xff800000);
    float myd = INF;
    int   myi = 0;
    float kth = INF;
    const bool isl0 = (lane & 15) == 0;
    constexpr int G = (NC >= 8) ? 8 : NC;
    for (int c0 = 0; c0 < NC; c0 += G) {
      float dg[G];
#pragma unroll
      for (int u = 0; u < G; u++) {
        float4 kp = kb[(c0 + u) * 64];
        float dot = __fadd_rn(__fadd_rn(__fmul_rn(q.x, kp.x), __fmul_rn(q.y, kp.y)),
                              __fmul_rn(q.z, kp.z));
        dg[u] = __fadd_rn(__fsub_rn(q.w, __fmul_rn(2.0f, dot)), kp.w);
      }
#pragma unroll
      for (int u = 0; u < G; u++) {
        float d = dg[u];
        unsigned long long msk = __ballot(d < kth);
        while (msk) {
          int j = __builtin_ctzll(msk);
          float dv = __int_as_float(__builtin_amdgcn_readlane(__float_as_int(d), j));
          int   iv = (c0 + u) * 64 + j;
          bool gt = (myd > dv);
          float pd = __int_as_float(__builtin_amdgcn_update_dpp(
              0, __float_as_int(myd), 0x111, 0xf, 0xf, true));
          int   pi = __builtin_amdgcn_update_dpp(0, myi, 0x111, 0xf, 0xf, true);
          pd = isl0 ? NEGINF : pd;
          bool tp = (pd > dv);
          float nd = tp ? pd : dv;
          int   nI = tp ? pi : iv;
          myd = gt ? nd : myd;
          myi = gt ? nI : myi;
          kth = __int_as_float(__builtin_amdgcn_readlane(__float_as_int(myd), 15));
          msk = __ballot(d < kth);
          msk = (j < 63) ? (msk & (~0ull << (j + 1))) : 0ull;
        }
      }
    }
    ni = myi;
  } else {
    ni = knn[(size_t)bq * KNB + (lane & 15)];
  }
  // edge-conv phase with inline-gn neighbor loads
  const int g = lane >> 4;
  size_t nbase = ((size_t)b * Nk + ni) * CF;
  float acc[J];
#pragma unroll
  for (int j = 0; j < J; j++) acc[j] = 0.0f;
  const float* wg = &Wl[g * SEC];
#pragma unroll
  for (int c = 0; c < CF; c += 4) {
    float4 mx4 = *(const float4*)(ymaxP + nbase + c);
    float4 mn4 = *(const float4*)(yminP + nbase + c);
    float4 sc4 = *(const float4*)(&t_scv[c]);
    float4 mo4 = *(const float4*)(&t_mo[c]);
    float4 gb4 = *(const float4*)(&t_gb[c]);
    float4 c4  = *(const float4*)(&wfc[wid][c]);
    float e0 = gnf(mx4.x, mn4.x, sc4.x, mo4.x, gb4.x) - c4.x;
    float e1 = gnf(mx4.y, mn4.y, sc4.y, mo4.y, gb4.y) - c4.y;
    float e2 = gnf(mx4.z, mn4.z, sc4.z, mo4.z, gb4.z) - c4.z;
    float e3 = gnf(mx4.w, mn4.w, sc4.w, mo4.w, gb4.w) - c4.w;
#pragma unroll
    for (int j = 0; j < J; j++) {
      float4 w4 = *(const float4*)(wg + j * CF + c);
      acc[j] = fmaf(e0, w4.x, acc[j]);
      acc[j] = fmaf(e1, w4.y, acc[j]);
      acc[j] = fmaf(e2, w4.z, acc[j]);
      acc[j] = fmaf(e3, w4.w, acc[j]);
    }
  }
  float s = 0.f, s2 = 0.f;
#pragma unroll
  for (int j = 0; j < J; j++) {
    float y = acc[j] + scy[wid][g * J + j];
    acc[j] = y;
    s += y; s2 = fmaf(y, y, s2);
  }
  float mn[J];
#pragma unroll
  for (int j = 0; j < J; j++) mn[j] = acc[j];
#pragma unroll
  for (int m = 1; m < 16; m <<= 1) {
#pragma unroll
    for (int j = 0; j < J; j++) {
      float a = __shfl_xor(acc[j], m); if (a > acc[j]) acc[j] = a;
      float c2 = __shfl_xor(mn[j], m); if (c2 < mn[j]) mn[j] = c2;
    }
    s  += __shfl_xor(s, m);
    s2 += __shfl_xor(s2, m);
  }
  if ((lane & 15) == 0) {
    float* mnp = ymin + (size_t)bq * CO + g * J;
    float* mxp = ymax + (size_t)bq * CO + g * J;
#pragma unroll
    for (int j = 0; j < J; j++) { mnp[j] = mn[j]; mxp[j] = acc[j]; }
    atomicAdd(&sstat[g], s);
    atomicAdd(&sstat[4 + g], s2);
  }
  __syncthreads();
  if (threadIdx.x < 8) atomicAdd(&gstats[b * 8 + threadIdx.x], sstat[threadIdx.x]);
}

// ---------------------------------------------------------------------------
// mega1 (256 thr): blocks [0,8) fps1 (+ gather tail); rest FUSED knn1+ec1.
// ---------------------------------------------------------------------------
__global__ __launch_bounds__(256, 2) void mega1_kernel(
    const float4* __restrict__ c40, const float* __restrict__ nrm,
    const float* __restrict__ pl, const float* __restrict__ f0,
    const float* __restrict__ W1, const float* __restrict__ ctrY1,
    int* __restrict__ idx1,
    float4* __restrict__ c4q1, float* __restrict__ nq1, float* __restrict__ pq1,
    float* __restrict__ ymin, float* __restrict__ ymax, float* __restrict__ gst1) {
  int blk = blockIdx.x;
  if (blk < 8) {
    const int b = blk, tid = threadIdx.x;
    const float4* cb = c40 + (size_t)b * N0;
    int w[4];
    fps_body<N0>(cb, w);
    int* idxb = idx1 + (size_t)b * NQ;
#pragma unroll
    for (int u = 0; u < 4; u++) {
      int r = tid + u * 256;
      int s = (u == 0 && tid == 0) ? 0 : w[u];
      idxb[r] = s;
      c4q1[(size_t)b * NQ + r] = cb[s];
      const float* np = nrm + ((size_t)b * N0 + s) * 3;
      float* ndp = nq1 + ((size_t)b * NQ + r) * 3;
      ndp[0] = np[0]; ndp[1] = np[1]; ndp[2] = np[2];
      pq1[(size_t)b * NQ + r] = pl[(size_t)b * N0 + s];
    }
  } else {
    knnec_body<64, 8, 32>(blk - 8, c40, c40, f0, f0, W1, ctrY1, nullptr,
                          ymin, ymax, gst1, N0, N0);
  }
}

// ---------------------------------------------------------------------------
// mega2 (256 thr, launch_bounds(256,1) so the 1-wave fps2's 64-reg arrays
// stay in registers): [0,8) SINGLE-WAVE fps2 v10 (+ same-wave gather tail);
// [8,8+2048) INLINE-GN fused knn2+ec2; rest knn3->knnB.
// ---------------------------------------------------------------------------
__global__ __launch_bounds__(256, 1) void mega2_kernel(
    const float4* __restrict__ c40, const float4* __restrict__ c4q1,
    const float* __restrict__ nq1, const float* __restrict__ pq1,
    const float* __restrict__ yminA, const float* __restrict__ ymaxA,
    const float* __restrict__ gst1, const float* __restrict__ g1w,
    const float* __restrict__ g1b, float inv1,
    const int* __restrict__ idx1, const float* __restrict__ W2,
    float* __restrict__ yminB, float* __restrict__ ymaxB, float* __restrict__ gst2,
    int* __restrict__ idx2, float4* __restrict__ c4q2,
    float* __restrict__ cq2out, float* __restrict__ nq2out,
    float* __restrict__ pq2out, int* __restrict__ knnB) {
  int blk = blockIdx.x;
  if (blk < 8) {
    if (threadIdx.x < 64) {
      __shared__ int swin2[NQ];
      const int b = blk, lane = threadIdx.x;
      const float4* cqb = c4q1 + (size_t)b * NQ;
      fps1w_body<NQ>(cqb, swin2);
      int* idxb = idx2 + (size_t)b * NQ;
#pragma unroll
      for (int u = 0; u < NQ / 64; u++) {
        int r = lane + u * 64;
        int s = (r == 0) ? 0 : swin2[r];
        idxb[r] = s;
        float4 c = cqb[s];
        c4q2[(size_t)b * NQ + r] = c;
        float* cd = cq2out + ((size_t)b * NQ + r) * 3;
        cd[0] = c.x; cd[1] = c.y; cd[2] = c.z;
        const float* np = nq1 + ((size_t)b * NQ + s) * 3;
        float* ndp = nq2out + ((size_t)b * NQ + r) * 3;
        ndp[0] = np[0]; ndp[1] = np[1]; ndp[2] = np[2];
        pq2out[(size_t)b * NQ + r] = pq1[(size_t)b * NQ + s];
      }
    }
  } else if (blk < 8 + 2048) {
    ec_gn_core<64, 32, 64, true>(blk - 8, c4q1, c40, nullptr,
                                 yminA, ymaxA, gst1, g1w, g1b, inv1,
                                 W2, idx1, yminB, ymaxB, gst2, NQ, N0);
  } else {
    int bq = (blk - (8 + 2048)) * 4 + (threadIdx.x >> 6);
    knn_body<16>(bq, threadIdx.x & 63, c4q1, c4q1, NQ, NQ, knnB);
  }
}

// ---------------------------------------------------------------------------
// ec3g (256 thr): layer-3 edgeconv with INLINE-GN f2 + in-wave ctrY3.
// ---------------------------------------------------------------------------
__global__ __launch_bounds__(256) void ec3g_kernel(
    const int* __restrict__ knnB,
    const float* __restrict__ yminB, const float* __restrict__ ymaxB,
    const float* __restrict__ gst2, const float* __restrict__ g2w,
    const float* __restrict__ g2b, float inv2,
    const float* __restrict__ W3,
    float* __restrict__ yminC, float* __restrict__ ymaxC, float* __restrict__ gst3) {
  ec_gn_core<16, 64, 64, false>(blockIdx.x, nullptr, nullptr, knnB,
                                yminB, ymaxB, gst2, g2w, g2b, inv2,
                                W3, nullptr, yminC, ymaxC, gst3, NQ, NQ);
}

// ---------------------------------------------------------------------------
// mega3g (256 thr): FUSED knn4+ec4 with INLINE-GN f3 + in-wave ctrY4.
// ---------------------------------------------------------------------------
__global__ __launch_bounds__(256) void mega3g_kernel(
    const float4* __restrict__ c4q1, const float4* __restrict__ c4q2,
    const float* __restrict__ yminC, const float* __restrict__ ymaxC,
    const float* __restrict__ gst3, const float* __restrict__ g3w,
    const float* __restrict__ g3b, float inv3,
    const int* __restrict__ idx2, const float* __restrict__ W4,
    float* __restrict__ yminD, float* __restrict__ ymaxD, float* __restrict__ gst4) {
  ec_gn_core<16, 64, 128, true>(blockIdx.x, c4q2, c4q1, nullptr,
                                yminC, ymaxC, gst3, g3w, g3b, inv3,
                                W4, idx2, yminD, ymaxD, gst4, NQ, NQ);
}

// ---------------------------------------------------------------------------
// pass B (gn_final fused): f = lrelu((sel - m)*gw*rs + gb) — final output.
// ---------------------------------------------------------------------------
template <int CO>
__global__ void gn_out_kernel(const float* __restrict__ ymin, const float* __restrict__ ymax,
                              const float* __restrict__ gstats, const float* __restrict__ gw,
                              const float* __restrict__ gb, float* __restrict__ fout,
                              int total, int Q, float inv_cnt) {
  int i = blockIdx.x * 256 + threadIdx.x;
  if (i >= total) return;
  constexpr int J = CO / 4;
  int o = i % CO; int bq = i / CO; int b = bq / Q;
  int g = o / J;
  float m  = gstats[b * 8 + g] * inv_cnt;
  float s2 = gstats[b * 8 + 4 + g] * inv_cnt;
  float rs = rsqrtf(s2 - m * m + 1e-5f);
  float sc = gw[o] * rs;
  float sel = (sc >= 0.f) ? ymax[i] : ymin[i];
  float v = (sel - m) * sc + gb[o];
  fout[i] = (v > 0.f) ? v : 0.2f * v;
}

// ---------------------------------------------------------------------------
extern "C" void kernel_launch(void* const* d_in, const int* in_sizes, int n_in,
                              void* d_out, int out_size, void* d_ws, size_t ws_size,
                              hipStream_t stream) {
  (void)in_sizes; (void)n_in; (void)out_size; (void)ws_size;
  const float* x    = (const float*)d_in[0];
  const float* W_in = (const float*)d_in[1];
  const float* b_in = (const float*)d_in[2];
  const float* W1   = (const float*)d_in[3];
  const float* g1w  = (const float*)d_in[4];
  const float* g1b  = (const float*)d_in[5];
  const float* W2   = (const float*)d_in[6];
  const float* g2w  = (const float*)d_in[7];
  const float* g2b  = (const float*)d_in[8];
  const float* W3   = (const float*)d_in[9];
  const float* g3w  = (const float*)d_in[10];
  const float* g3b  = (const float*)d_in[11];
  const float* W4   = (const float*)d_in[12];
  const float* g4w  = (const float*)d_in[13];
  const float* g4b  = (const float*)d_in[14];

  float* ws = (float*)d_ws;
  size_t o_c40   = 0;                                          // float4-aligned
  size_t o_nrm   = o_c40   + (size_t)B * N0 * 4;
  size_t o_pl    = o_nrm   + (size_t)B * N0 * 3;
  size_t o_f0    = o_pl    + (size_t)B * N0;
  size_t o_ctrY1 = o_f0    + (size_t)B * N0 * 8;               // 1M floats
  size_t o_yAmin = o_ctrY1 + (size_t)B * N0 * 32;              // 1M
  size_t o_yAmax = o_yAmin + (size_t)B * N0 * 32;              // 1M
  size_t o_yBmin = o_yAmax + (size_t)B * N0 * 32;              // 0.5M
  size_t o_yBmax = o_yBmin + (size_t)B * NQ * 64;
  size_t o_yCmin = o_yBmax + (size_t)B * NQ * 64;
  size_t o_yCmax = o_yCmin + (size_t)B * NQ * 64;
  size_t o_knnB  = o_yCmax + (size_t)B * NQ * 64;              // int region
  size_t o_gst   = o_knnB  + (size_t)B * NQ * KNB;
  size_t o_idx1  = o_gst   + 4 * B * 8;                        // int region
  size_t o_idx2  = o_idx1  + (size_t)B * NQ;                   // int region
  size_t o_c4q1  = o_idx2  + (size_t)B * NQ;                   // float4-aligned
  size_t o_c4q2  = o_c4q1  + (size_t)B * NQ * 4;               // float4-aligned
  size_t o_nq1   = o_c4q2  + (size_t)B * NQ * 4;
  size_t o_pq1   = o_nq1   + (size_t)B * NQ * 3;

  float4* c40   = (float4*)(ws + o_c40);
  float*  nrm   = ws + o_nrm;    float* pl    = ws + o_pl;
  float*  f0    = ws + o_f0;     float* ctrY1 = ws + o_ctrY1;
  float*  yAmin = ws + o_yAmin;  float* yAmax = ws + o_yAmax;
  float*  yBmin = ws + o_yBmin;  float* yBmax = ws + o_yBmax;
  float*  yCmin = ws + o_yCmin;  float* yCmax = ws + o_yCmax;
  // Layer-4 minmax aliases: ctrY1 (dead after mega1) and yAmin (dead after mega2).
  float*  yDmin = ctrY1;
  float*  yDmax = yAmin;
  int*    knnB  = (int*)(ws + o_knnB);
  float*  gst   = ws + o_gst;
  int*    idx1  = (int*)(ws + o_idx1);
  int*    idx2  = (int*)(ws + o_idx2);
  float4* c4q1  = (float4*)(ws + o_c4q1);
  float4* c4q2  = (float4*)(ws + o_c4q2);
  float*  nq1   = ws + o_nq1;    float* pq1   = ws + o_pq1;

  float* out  = (float*)d_out;
  float* cq2  = out;                                   // (B,NQ,3)
  float* fout = out + (size_t)B * NQ * 3;              // (B,NQ,128)
  float* nq2  = fout + (size_t)B * NQ * 128;           // (B,NQ,3)
  float* pq2  = nq2 + (size_t)B * NQ * 3;              // (B,NQ,1)

  const float inv1 = 1.0f / (4096.0f * 16.0f * 8.0f);
  const float inv2 = 1.0f / (1024.0f * 16.0f * 16.0f);
  const float inv3 = 1.0f / (1024.0f * 16.0f * 16.0f);
  const float inv4 = 1.0f / (1024.0f * 16.0f * 32.0f);

  hipMemsetAsync(gst, 0, 4 * B * 8 * sizeof(float), stream);

  // stage 0: prep (+ ctrY1)
  prep_kernel<<<(B * N0 + 255) / 256, 256, 0, stream>>>(x, W_in, b_in, W1,
                                                        c40, nrm, pl, f0, ctrY1);

  // mega1: fps1 || fused knn1+ec1   (deps: prep only)
  mega1_kernel<<<8 + 8192, 256, 0, stream>>>(c40, nrm, pl, f0, W1, ctrY1,
                                             idx1, c4q1, nq1, pq1,
                                             yAmin, yAmax, gst + 0);

  // mega2: 1-wave fps2 || inline-gn fused knn2+ec2 || knn3   (deps: mega1)
  mega2_kernel<<<8 + 2048 + 2048, 256, 0, stream>>>(
      c40, c4q1, nq1, pq1, yAmin, yAmax, gst + 0, g1w, g1b, inv1,
      idx1, W2, yBmin, yBmax, gst + B * 8,
      idx2, c4q2, cq2, nq2, pq2, knnB);

  // layer 3: inline-gn f2 + in-wave ctrY3 (knn3 -> knnB from mega2)
  ec3g_kernel<<<B * NQ / 4, 256, 0, stream>>>(
      knnB, yBmin, yBmax, gst + B * 8, g2w, g2b, inv2, W3,
      yCmin, yCmax, gst + 2 * B * 8);

  // layer 4: fused knn4+ec4 with inline-gn f3 + in-wave ctrY4
  mega3g_kernel<<<B * NQ / 4, 256, 0, stream>>>(
      c4q1, c4q2, yCmin, yCmax, gst + 2 * B * 8, g3w, g3b, inv3,
      idx2, W4, yDmin, yDmax, gst + 3 * B * 8);

  // final gn -> fout
  gn_out_kernel<128><<<(B * NQ * 128 + 255) / 256, 256, 0, stream>>>(
      yDmin, yDmax, gst + 3 * B * 8, g4w, g4b, fout, B * NQ * 128, NQ, inv4);
}

// Round 12
// 1775.805 us; speedup vs baseline: 1.0455x; 1.0455x over previous
//
#include <hip/hip_runtime.h>
#include <cstdint>

static constexpr int B   = 8;
static constexpr int N0  = 4096;
static constexpr int NQ  = 1024;
static constexpr int KNB = 16;

// ---------------------------------------------------------------------------
// u64 wave max; result valid in LANE 63 only. No readlane/ballot — pure VALU.
// ---------------------------------------------------------------------------
__device__ __forceinline__ unsigned long long wave_max_u64_l63(unsigned long long k) {
#define STEPU_(ctrl)                                                                    \
  {                                                                                     \
    unsigned lo_ = (unsigned)k, hi_ = (unsigned)(k >> 32);                              \
    unsigned plo_ = (unsigned)__builtin_amdgcn_update_dpp((int)lo_, (int)lo_, ctrl,     \
                                                          0xf, 0xf, false);             \
    unsigned phi_ = (unsigned)__builtin_amdgcn_update_dpp((int)hi_, (int)hi_, ctrl,     \
                                                          0xf, 0xf, false);             \
    unsigned long long pk_ = ((unsigned long long)phi_ << 32) | plo_;                   \
    if (pk_ > k) k = pk_;                                                               \
  }
  STEPU_(0x111) STEPU_(0x112) STEPU_(0x114) STEPU_(0x118) STEPU_(0x142) STEPU_(0x143)
#undef STEPU_
  return k;
}

// ---------------------------------------------------------------------------
// gn inline formula — EXACT same expression as gn_out_kernel (bit-identical).
// ---------------------------------------------------------------------------
__device__ __forceinline__ float gnf(float mx, float mn, float scv, float mo, float gb) {
  float sel = (scv >= 0.f) ? mx : mn;
  float v = (sel - mo) * scv + gb;
  return (v > 0.f) ? v : 0.2f * v;
}

// ---------------------------------------------------------------------------
// prep: split x; write packed c4 = {x,y,z,|c|^2}, normal, plane, f0, AND
// ctrY1 (layer-1 center projection) — same fmaf order as the old ctry body.
// ---------------------------------------------------------------------------
__global__ void prep_kernel(const float* __restrict__ x,
                            const float* __restrict__ W_in,
                            const float* __restrict__ b_in,
                            const float* __restrict__ W1,
                            float4* __restrict__ c4, float* __restrict__ nrm,
                            float* __restrict__ pl, float* __restrict__ f0,
                            float* __restrict__ ctrY1) {
  int i = blockIdx.x * 256 + threadIdx.x;
  if (i >= B * N0) return;
  const float* xp = x + (size_t)i * 7;
  float cx = xp[0], cy = xp[1], cz = xp[2];
  // tie-sensitive (feeds kNN distance): exact fp32, ref association order
  float kk = __fadd_rn(__fadd_rn(__fmul_rn(cx, cx), __fmul_rn(cy, cy)), __fmul_rn(cz, cz));
  c4[i] = make_float4(cx, cy, cz, kk);
  nrm[i * 3 + 0] = xp[3]; nrm[i * 3 + 1] = xp[4]; nrm[i * 3 + 2] = xp[5];
  pl[i] = xp[6];
  float f[8];
#pragma unroll
  for (int o = 0; o < 8; o++) {
    f[o] = cx * W_in[o * 3 + 0] + cy * W_in[o * 3 + 1] + cz * W_in[o * 3 + 2] + b_in[o];
    f0[(size_t)i * 8 + o] = f[o];
  }
#pragma unroll
  for (int o = 0; o < 32; o++) {
    const float* wp = W1 + (size_t)o * 16 + 8;
    float acc = 0.f;
#pragma unroll
    for (int c = 0; c < 8; c++) acc = fmaf(f[c], wp[c], acc);
    ctrY1[(size_t)i * 32 + o] = acc;
  }
}

// ---------------------------------------------------------------------------
// kNN body: STREAMING INSERTION TOP-K (harness-verified). Wave per query.
// ---------------------------------------------------------------------------
template <int NC>
__device__ __forceinline__ void knn_body(int bq, int lane,
                                         const float4* __restrict__ q4,
                                         const float4* __restrict__ k4,
                                         int Q, int Nk, int* __restrict__ out) {
  int b = bq / Q;
  float4 q = q4[bq];
  const float4* kb = k4 + (size_t)b * Nk + lane;
  const float INF    = __int_as_float(0x7f800000);
  const float NEGINF = __int_as_float(0xff800000);
  float myd = INF;
  int   myi = 0;
  float kth = INF;
  const bool isl0 = (lane & 15) == 0;
  constexpr int G = (NC >= 8) ? 8 : NC;
  for (int c0 = 0; c0 < NC; c0 += G) {
    float dg[G];
#pragma unroll
    for (int u = 0; u < G; u++) {
      float4 kp = kb[(c0 + u) * 64];
      float dot = __fadd_rn(__fadd_rn(__fmul_rn(q.x, kp.x), __fmul_rn(q.y, kp.y)),
                            __fmul_rn(q.z, kp.z));
      dg[u] = __fadd_rn(__fsub_rn(q.w, __fmul_rn(2.0f, dot)), kp.w);
    }
#pragma unroll
    for (int u = 0; u < G; u++) {
      float d = dg[u];
      unsigned long long msk = __ballot(d < kth);
      while (msk) {
        int j = __builtin_ctzll(msk);
        float dv = __int_as_float(__builtin_amdgcn_readlane(__float_as_int(d), j));
        int   iv = (c0 + u) * 64 + j;
        bool gt = (myd > dv);
        float pd = __int_as_float(__builtin_amdgcn_update_dpp(
            0, __float_as_int(myd), 0x111, 0xf, 0xf, true));
        int   pi = __builtin_amdgcn_update_dpp(0, myi, 0x111, 0xf, 0xf, true);
        pd = isl0 ? NEGINF : pd;
        bool tp = (pd > dv);
        float nd = tp ? pd : dv;
        int   ni = tp ? pi : iv;
        myd = gt ? nd : myd;
        myi = gt ? ni : myi;
        kth = __int_as_float(__builtin_amdgcn_readlane(__float_as_int(myd), 15));
        msk = __ballot(d < kth);
        msk = (j < 63) ? (msk & (~0ull << (j + 1))) : 0ull;
      }
    }
  }
  if (lane < KNB) out[(size_t)bq * KNB + lane] = myi;
}

// ---------------------------------------------------------------------------
// FPS v5 (harness-verified): BLK=256 (4 waves), one block per batch.
// ---------------------------------------------------------------------------
template <int NPTS>
__device__ __forceinline__ void fps_body(const float4* __restrict__ cb, int* w) {
  constexpr int BLK = 256;
  constexpr int M = NPTS / BLK;
  constexpr int NW = BLK / 64;  // 4
  __shared__ __align__(16) float2 sxy[NPTS];
  __shared__ float szz[NPTS];
  __shared__ __align__(16) unsigned long long skey[2][NW];
  const int tid = threadIdx.x;
  const int wid = tid >> 6, lane = tid & 63;
  float cx[M], cy[M], cz[M], dist[M];
#pragma unroll
  for (int i = 0; i < M; i++) {
    float4 p = cb[tid * M + i];
    cx[i] = p.x; cy[i] = p.y; cz[i] = p.z;
    dist[i] = 3.4e38f;
    sxy[tid * M + i] = make_float2(p.x, p.y);
    szz[tid * M + i] = p.z;
  }
  w[0] = w[1] = w[2] = w[3] = 0;
  float4 p0 = cb[0];
  float px = p0.x, py = p0.y, pz = p0.z;
  __syncthreads();
  for (int t = 1; t < NQ; t++) {
    float bv = -1.f; int bi = 0;
#pragma unroll
    for (int i = 0; i < M; i++) {
      float dx = __fsub_rn(cx[i], px), dy = __fsub_rn(cy[i], py), dz = __fsub_rn(cz[i], pz);
      float d = __fadd_rn(__fadd_rn(__fmul_rn(dx, dx), __fmul_rn(dy, dy)), __fmul_rn(dz, dz));
      float dd = dist[i]; dd = (d < dd) ? d : dd; dist[i] = dd;
      if (dd > bv) { bv = dd; bi = tid * M + i; }
    }
    unsigned long long k =
        ((unsigned long long)__float_as_uint(bv) << 12) | (unsigned)(4095 - bi);
    k = wave_max_u64_l63(k);
    int p = t & 1;
    if (lane == 63) skey[p][wid] = k;
    __syncthreads();
    ulonglong2 ab = *(const ulonglong2*)&skey[p][0];
    ulonglong2 cd = *(const ulonglong2*)&skey[p][2];
    unsigned long long m0 = (ab.x > ab.y) ? ab.x : ab.y;
    unsigned long long m1 = (cd.x > cd.y) ? cd.x : cd.y;
    unsigned long long mk = (m0 > m1) ? m0 : m1;
    int win = 4095 - (int)(mk & 0xFFFull);
    float2 pxy = sxy[win];
    px = pxy.x; py = pxy.y; pz = szz[win];
    if (t == tid) w[0] = win;
    if (t == tid + 256) w[1] = win;
    if (t == tid + 512) w[2] = win;
    if (t == tid + 768) w[3] = win;
  }
}

// ---------------------------------------------------------------------------
// FPS v11: SINGLE-WAVE fps for NPTS=1024, coords in LDS + dist[16] in regs
// (fits the ~64-VGPR budget the allocator enforces — v9/v10 spilled).
// The coord ds_reads are loop-invariant-addressed (NOT on the px-dependent
// chain) and are read in chunks of 4 to cap staging regs. Winner coords
// tracked in regs during the scan (cndmasks off-chain); wave reduce =
// 6 DPP v_max_f32 -> readlane -> ballot(bv==wmax) -> ctz -> owner lane L ->
// 4 readlanes. Zero barriers, zero dependent LDS reads on the serial chain.
// Tie semantics: lane-major ownership => (max d, min lane, min i) == min
// global index among maxima == jnp.argmax first-occurrence == v5 key order.
// ---------------------------------------------------------------------------
template <int NPTS>
__device__ __forceinline__ void fps1w_body(const float4* __restrict__ cb,
                                           float4* __restrict__ scoord,
                                           int* __restrict__ swin) {
  constexpr int M = NPTS / 64;  // 16
  const int lane = threadIdx.x;  // caller guarantees threadIdx.x < 64
  float dist[M];
#pragma unroll
  for (int i = 0; i < M; i++) {
    float4 p = cb[lane * M + i];
    scoord[lane * M + i] = p;
    dist[i] = 3.4e38f;
  }
  float4 p0 = cb[0];
  float px = p0.x, py = p0.y, pz = p0.z;
  // single wave: compiler lgkmcnt orders the scoord writes before reads
  for (int t = 1; t < NQ; t++) {
    float bv = -1.f; int bi = 0;
    float bx = px, by = py, bz = pz;  // dd >= 0 > -1 so always overwritten
#pragma unroll
    for (int c = 0; c < M; c += 4) {
      float4 pp[4];
#pragma unroll
      for (int u = 0; u < 4; u++) pp[u] = scoord[lane * M + c + u];
#pragma unroll
      for (int u = 0; u < 4; u++) {
        const int i = c + u;
        float dx = __fsub_rn(pp[u].x, px), dy = __fsub_rn(pp[u].y, py),
              dz = __fsub_rn(pp[u].z, pz);
        float d = __fadd_rn(__fadd_rn(__fmul_rn(dx, dx), __fmul_rn(dy, dy)),
                            __fmul_rn(dz, dz));
        float dd = dist[i]; dd = (d < dd) ? d : dd; dist[i] = dd;
        if (dd > bv) { bv = dd; bi = lane * M + i; bx = pp[u].x; by = pp[u].y; bz = pp[u].z; }
      }
    }
    float wm = bv;
#define SMAX_(ctrl)                                                                     \
  {                                                                                     \
    int t_ = __builtin_amdgcn_update_dpp(__float_as_int(wm), __float_as_int(wm), ctrl,  \
                                         0xf, 0xf, false);                              \
    wm = fmaxf(wm, __int_as_float(t_));                                                 \
  }
    SMAX_(0x111) SMAX_(0x112) SMAX_(0x114) SMAX_(0x118) SMAX_(0x142) SMAX_(0x143)
#undef SMAX_
    float wmax = __int_as_float(__builtin_amdgcn_readlane(__float_as_int(wm), 63));
    unsigned long long tied = __ballot(bv == wmax);
    int L = (int)__builtin_ctzll(tied);  // min lane == min global index
    int win = __builtin_amdgcn_readlane(bi, L);
    px = __int_as_float(__builtin_amdgcn_readlane(__float_as_int(bx), L));
    py = __int_as_float(__builtin_amdgcn_readlane(__float_as_int(by), L));
    pz = __int_as_float(__builtin_amdgcn_readlane(__float_as_int(bz), L));
    if (lane == 0) swin[t] = win;
  }
}

// ---------------------------------------------------------------------------
// FUSED kNN + edge-conv body (layer 1; f0/ctrY1 materialized). Verbatim R8.
// ---------------------------------------------------------------------------
template <int NC, int CF, int CO>
__device__ __forceinline__ void knnec_body(
    int blkid, const float4* __restrict__ q4, const float4* __restrict__ k4,
    const float* __restrict__ fq, const float* __restrict__ fk,
    const float* __restrict__ Wfull, const float* __restrict__ ctrY,
    const int* __restrict__ ridx,
    float* __restrict__ ymin, float* __restrict__ ymax,
    float* __restrict__ gstats, int Q, int Nk) {
  constexpr int J = CO / 4;
  constexpr int SEC = J * CF + 8;
  __shared__ float Wl[4 * SEC];
  __shared__ float sstat[8];
  for (int t = threadIdx.x; t < CO * CF; t += 256) {
    int o = t / CF, c = t % CF;
    Wl[(o / J) * SEC + (o % J) * CF + c] = Wfull[(size_t)o * (2 * CF) + c];
  }
  if (threadIdx.x < 8) sstat[threadIdx.x] = 0.0f;
  __syncthreads();
  const int wid = threadIdx.x >> 6, lane = threadIdx.x & 63;
  const int bq = blkid * 4 + wid;
  const int b = bq / Q;
  // kNN phase
  float4 q = q4[bq];
  const float4* kb = k4 + (size_t)b * Nk + lane;
  const float INF    = __int_as_float(0x7f800000);
  const float NEGINF = __int_as_float(0xff800000);
  float myd = INF;
  int   myi = 0;
  float kth = INF;
  const bool isl0 = (lane & 15) == 0;
  constexpr int G = (NC >= 8) ? 8 : NC;
  for (int c0 = 0; c0 < NC; c0 += G) {
    float dg[G];
#pragma unroll
    for (int u = 0; u < G; u++) {
      float4 kp = kb[(c0 + u) * 64];
      float dot = __fadd_rn(__fadd_rn(__fmul_rn(q.x, kp.x), __fmul_rn(q.y, kp.y)),
                            __fmul_rn(q.z, kp.z));
      dg[u] = __fadd_rn(__fsub_rn(q.w, __fmul_rn(2.0f, dot)), kp.w);
    }
#pragma unroll
    for (int u = 0; u < G; u++) {
      float d = dg[u];
      unsigned long long msk = __ballot(d < kth);
      while (msk) {
        int j = __builtin_ctzll(msk);
        float dv = __int_as_float(__builtin_amdgcn_readlane(__float_as_int(d), j));
        int   iv = (c0 + u) * 64 + j;
        bool gt = (myd > dv);
        float pd = __int_as_float(__builtin_amdgcn_update_dpp(
            0, __float_as_int(myd), 0x111, 0xf, 0xf, true));
        int   pi = __builtin_amdgcn_update_dpp(0, myi, 0x111, 0xf, 0xf, true);
        pd = isl0 ? NEGINF : pd;
        bool tp = (pd > dv);
        float nd = tp ? pd : dv;
        int   nI = tp ? pi : iv;
        myd = gt ? nd : myd;
        myi = gt ? nI : myi;
        kth = __int_as_float(__builtin_amdgcn_readlane(__float_as_int(myd), 15));
        msk = __ballot(d < kth);
        msk = (j < 63) ? (msk & (~0ull << (j + 1))) : 0ull;
      }
    }
  }
  // edge-conv phase
  const int g = lane >> 4;
  const int ni = myi;
  const float* nbp = fk + (size_t)(b * Nk + ni) * CF;
  const float* cp = ridx ? fq + ((size_t)b * Nk + ridx[bq]) * CF
                         : fq + (size_t)bq * CF;
  float acc[J];
#pragma unroll
  for (int j = 0; j < J; j++) acc[j] = 0.0f;
  const float* wg = &Wl[g * SEC];
#pragma unroll
  for (int c = 0; c < CF; c += 4) {
    float4 nb4 = *(const float4*)(nbp + c);
    float4 c4  = *(const float4*)(cp + c);
    float e0 = nb4.x - c4.x, e1 = nb4.y - c4.y, e2 = nb4.z - c4.z, e3 = nb4.w - c4.w;
#pragma unroll
    for (int j = 0; j < J; j++) {
      float4 w4 = *(const float4*)(wg + j * CF + c);
      acc[j] = fmaf(e0, w4.x, acc[j]);
      acc[j] = fmaf(e1, w4.y, acc[j]);
      acc[j] = fmaf(e2, w4.z, acc[j]);
      acc[j] = fmaf(e3, w4.w, acc[j]);
    }
  }
  float s = 0.f, s2 = 0.f;
  const float* cyp = ctrY + (size_t)bq * CO + g * J;
#pragma unroll
  for (int j = 0; j < J; j++) {
    float y = acc[j] + cyp[j];
    acc[j] = y;
    s += y; s2 = fmaf(y, y, s2);
  }
  float mn[J];
#pragma unroll
  for (int j = 0; j < J; j++) mn[j] = acc[j];
#pragma unroll
  for (int m = 1; m < 16; m <<= 1) {
#pragma unroll
    for (int j = 0; j < J; j++) {
      float a = __shfl_xor(acc[j], m); if (a > acc[j]) acc[j] = a;
      float c2 = __shfl_xor(mn[j], m); if (c2 < mn[j]) mn[j] = c2;
    }
    s  += __shfl_xor(s, m);
    s2 += __shfl_xor(s2, m);
  }
  if ((lane & 15) == 0) {
    float* mnp = ymin + (size_t)bq * CO + g * J;
    float* mxp = ymax + (size_t)bq * CO + g * J;
#pragma unroll
    for (int j = 0; j < J; j++) { mnp[j] = mn[j]; mxp[j] = acc[j]; }
    atomicAdd(&sstat[g], s);
    atomicAdd(&sstat[4 + g], s2);
  }
  __syncthreads();
  if (threadIdx.x < 8) atomicAdd(&gstats[b * 8 + threadIdx.x], sstat[threadIdx.x]);
}

// ---------------------------------------------------------------------------
// INLINE-GN edge-conv core (layers 2-4). Verbatim R9.
// ---------------------------------------------------------------------------
template <int NC, int CF, int CO, bool HAS_KNN>
__device__ __forceinline__ void ec_gn_core(
    int blkid, const float4* __restrict__ q4, const float4* __restrict__ k4,
    const int* __restrict__ knn,
    const float* __restrict__ yminP, const float* __restrict__ ymaxP,
    const float* __restrict__ gstP, const float* __restrict__ gwP,
    const float* __restrict__ gbP, float invP,
    const float* __restrict__ Wfull, const int* __restrict__ ridx,
    float* __restrict__ ymin, float* __restrict__ ymax,
    float* __restrict__ gstats, int Q, int Nk) {
  constexpr int J = CO / 4;
  constexpr int SEC = J * CF + 8;
  __shared__ float Wl[4 * SEC];
  __shared__ float sstat[8];
  __shared__ __align__(16) float t_scv[CF];
  __shared__ __align__(16) float t_mo[CF];
  __shared__ __align__(16) float t_gb[CF];
  __shared__ __align__(16) float wfc[4][CF];
  __shared__ float scy[4][CO];
  const int b = (blkid * 4) / Q;  // block-uniform (Q % 4 == 0)
  for (int t = threadIdx.x; t < CO * CF; t += 256) {
    int o = t / CF, c = t % CF;
    Wl[(o / J) * SEC + (o % J) * CF + c] = Wfull[(size_t)o * (2 * CF) + c];
  }
  if (threadIdx.x < CF) {
    int c = threadIdx.x;
    int gg = c / (CF / 4);
    float m  = gstP[b * 8 + gg] * invP;
    float s2 = gstP[b * 8 + 4 + gg] * invP;
    float rs = rsqrtf(s2 - m * m + 1e-5f);
    t_scv[c] = gwP[c] * rs;
    t_mo[c]  = m;
    t_gb[c]  = gbP[c];
  }
  if (threadIdx.x < 8) sstat[threadIdx.x] = 0.0f;
  __syncthreads();
  const int wid = threadIdx.x >> 6, lane = threadIdx.x & 63;
  const int bq = blkid * 4 + wid;
  // center f row (inline-gn), then this-layer ctrY row (in-wave dot)
  size_t cbase = (ridx ? ((size_t)b * Nk + ridx[bq]) : (size_t)bq) * CF;
  if (lane < CF)
    wfc[wid][lane] = gnf(ymaxP[cbase + lane], yminP[cbase + lane],
                         t_scv[lane], t_mo[lane], t_gb[lane]);
  for (int oo = lane; oo < CO; oo += 64) {
    const float* wp = Wfull + (size_t)oo * (2 * CF) + CF;
    float acc0 = 0.f;
#pragma unroll
    for (int c = 0; c < CF; c++) acc0 = fmaf(wfc[wid][c], wp[c], acc0);
    scy[wid][oo] = acc0;
  }
  // neighbor index
  int ni;
  if (HAS_KNN) {
    float4 q = q4[bq];
    const float4* kb = k4 + (size_t)b * Nk + lane;
    const float INF    = __int_as_float(0x7f800000);
    const float NEGINF = __int_as_float(0xff800000);
    float myd = INF;
    int   myi = 0;
    float kth = INF;
    const bool isl0 = (lane & 15) == 0;
    constexpr int G = (NC >= 8) ? 8 : NC;
    for (int c0 = 0; c0 < NC; c0 += G) {
      float dg[G];
#pragma unroll
      for (int u = 0; u < G; u++) {
        float4 kp = kb[(c0 + u) * 64];
        float dot = __fadd_rn(__fadd_rn(__fmul_rn(q.x, kp.x), __fmul_rn(q.y, kp.y)),
                              __fmul_rn(q.z, kp.z));
        dg[u] = __fadd_rn(__fsub_rn(q.w, __fmul_rn(2.0f, dot)), kp.w);
      }
#pragma unroll
      for (int u = 0; u < G; u++) {
        float d = dg[u];
        unsigned long long msk = __ballot(d < kth);
        while (msk) {
          int j = __builtin_ctzll(msk);
          float dv = __int_as_float(__builtin_amdgcn_readlane(__float_as_int(d), j));
          int   iv = (c0 + u) * 64 + j;
          bool gt = (myd > dv);
          float pd = __int_as_float(__builtin_amdgcn_update_dpp(
              0, __float_as_int(myd), 0x111, 0xf, 0xf, true));
          int   pi = __builtin_amdgcn_update_dpp(0, myi, 0x111, 0xf, 0xf, true);
          pd = isl0 ? NEGINF : pd;
          bool tp = (pd > dv);
          float nd = tp ? pd : dv;
          int   nI = tp ? pi : iv;
          myd = gt ? nd : myd;
          myi = gt ? nI : myi;
          kth = __int_as_float(__builtin_amdgcn_readlane(__float_as_int(myd), 15));
          msk = __ballot(d < kth);
          msk = (j < 63) ? (msk & (~0ull << (j + 1))) : 0ull;
        }
      }
    }
    ni = myi;
  } else {
    ni = knn[(size_t)bq * KNB + (lane & 15)];
  }
  // edge-conv phase with inline-gn neighbor loads
  const int g = lane >> 4;
  size_t nbase = ((size_t)b * Nk + ni) * CF;
  float acc[J];
#pragma unroll
  for (int j = 0; j < J; j++) acc[j] = 0.0f;
  const float* wg = &Wl[g * SEC];
#pragma unroll
  for (int c = 0; c < CF; c += 4) {
    float4 mx4 = *(const float4*)(ymaxP + nbase + c);
    float4 mn4 = *(const float4*)(yminP + nbase + c);
    float4 sc4 = *(const float4*)(&t_scv[c]);
    float4 mo4 = *(const float4*)(&t_mo[c]);
    float4 gb4 = *(const float4*)(&t_gb[c]);
    float4 c4  = *(const float4*)(&wfc[wid][c]);
    float e0 = gnf(mx4.x, mn4.x, sc4.x, mo4.x, gb4.x) - c4.x;
    float e1 = gnf(mx4.y, mn4.y, sc4.y, mo4.y, gb4.y) - c4.y;
    float e2 = gnf(mx4.z, mn4.z, sc4.z, mo4.z, gb4.z) - c4.z;
    float e3 = gnf(mx4.w, mn4.w, sc4.w, mo4.w, gb4.w) - c4.w;
#pragma unroll
    for (int j = 0; j < J; j++) {
      float4 w4 = *(const float4*)(wg + j * CF + c);
      acc[j] = fmaf(e0, w4.x, acc[j]);
      acc[j] = fmaf(e1, w4.y, acc[j]);
      acc[j] = fmaf(e2, w4.z, acc[j]);
      acc[j] = fmaf(e3, w4.w, acc[j]);
    }
  }
  float s = 0.f, s2 = 0.f;
#pragma unroll
  for (int j = 0; j < J; j++) {
    float y = acc[j] + scy[wid][g * J + j];
    acc[j] = y;
    s += y; s2 = fmaf(y, y, s2);
  }
  float mn[J];
#pragma unroll
  for (int j = 0; j < J; j++) mn[j] = acc[j];
#pragma unroll
  for (int m = 1; m < 16; m <<= 1) {
#pragma unroll
    for (int j = 0; j < J; j++) {
      float a = __shfl_xor(acc[j], m); if (a > acc[j]) acc[j] = a;
      float c2 = __shfl_xor(mn[j], m); if (c2 < mn[j]) mn[j] = c2;
    }
    s  += __shfl_xor(s, m);
    s2 += __shfl_xor(s2, m);
  }
  if ((lane & 15) == 0) {
    float* mnp = ymin + (size_t)bq * CO + g * J;
    float* mxp = ymax + (size_t)bq * CO + g * J;
#pragma unroll
    for (int j = 0; j < J; j++) { mnp[j] = mn[j]; mxp[j] = acc[j]; }
    atomicAdd(&sstat[g], s);
    atomicAdd(&sstat[4 + g], s2);
  }
  __syncthreads();
  if (threadIdx.x < 8) atomicAdd(&gstats[b * 8 + threadIdx.x], sstat[threadIdx.x]);
}

// ---------------------------------------------------------------------------
// mega1 (256 thr): blocks [0,8) fps1 (+ gather tail); rest FUSED knn1+ec1.
// ---------------------------------------------------------------------------
__global__ __launch_bounds__(256, 2) void mega1_kernel(
    const float4* __restrict__ c40, const float* __restrict__ nrm,
    const float* __restrict__ pl, const float* __restrict__ f0,
    const float* __restrict__ W1, const float* __restrict__ ctrY1,
    int* __restrict__ idx1,
    float4* __restrict__ c4q1, float* __restrict__ nq1, float* __restrict__ pq1,
    float* __restrict__ ymin, float* __restrict__ ymax, float* __restrict__ gst1) {
  int blk = blockIdx.x;
  if (blk < 8) {
    const int b = blk, tid = threadIdx.x;
    const float4* cb = c40 + (size_t)b * N0;
    int w[4];
    fps_body<N0>(cb, w);
    int* idxb = idx1 + (size_t)b * NQ;
#pragma unroll
    for (int u = 0; u < 4; u++) {
      int r = tid + u * 256;
      int s = (u == 0 && tid == 0) ? 0 : w[u];
      idxb[r] = s;
      c4q1[(size_t)b * NQ + r] = cb[s];
      const float* np = nrm + ((size_t)b * N0 + s) * 3;
      float* ndp = nq1 + ((size_t)b * NQ + r) * 3;
      ndp[0] = np[0]; ndp[1] = np[1]; ndp[2] = np[2];
      pq1[(size_t)b * NQ + r] = pl[(size_t)b * N0 + s];
    }
  } else {
    knnec_body<64, 8, 32>(blk - 8, c40, c40, f0, f0, W1, ctrY1, nullptr,
                          ymin, ymax, gst1, N0, N0);
  }
}

// ---------------------------------------------------------------------------
// mega2 (256 thr): [0,8) SINGLE-WAVE fps2 v11 (LDS coords + reg dist — fits
// the 64-VGPR budget, no spill) + same-wave gather tail; [8,8+2048)
// INLINE-GN fused knn2+ec2; rest knn3->knnB.
// ---------------------------------------------------------------------------
__global__ __launch_bounds__(256, 2) void mega2_kernel(
    const float4* __restrict__ c40, const float4* __restrict__ c4q1,
    const float* __restrict__ nq1, const float* __restrict__ pq1,
    const float* __restrict__ yminA, const float* __restrict__ ymaxA,
    const float* __restrict__ gst1, const float* __restrict__ g1w,
    const float* __restrict__ g1b, float inv1,
    const int* __restrict__ idx1, const float* __restrict__ W2,
    float* __restrict__ yminB, float* __restrict__ ymaxB, float* __restrict__ gst2,
    int* __restrict__ idx2, float4* __restrict__ c4q2,
    float* __restrict__ cq2out, float* __restrict__ nq2out,
    float* __restrict__ pq2out, int* __restrict__ knnB) {
  int blk = blockIdx.x;
  if (blk < 8) {
    __shared__ __align__(16) float4 sc2[NQ];
    __shared__ int swin2[NQ];
    if (threadIdx.x < 64) {
      const int b = blk, lane = threadIdx.x;
      const float4* cqb = c4q1 + (size_t)b * NQ;
      fps1w_body<NQ>(cqb, sc2, swin2);
      int* idxb = idx2 + (size_t)b * NQ;
#pragma unroll
      for (int u = 0; u < NQ / 64; u++) {
        int r = lane + u * 64;
        int s = (r == 0) ? 0 : swin2[r];
        idxb[r] = s;
        float4 c = sc2[s];
        c4q2[(size_t)b * NQ + r] = c;
        float* cd = cq2out + ((size_t)b * NQ + r) * 3;
        cd[0] = c.x; cd[1] = c.y; cd[2] = c.z;
        const float* np = nq1 + ((size_t)b * NQ + s) * 3;
        float* ndp = nq2out + ((size_t)b * NQ + r) * 3;
        ndp[0] = np[0]; ndp[1] = np[1]; ndp[2] = np[2];
        pq2out[(size_t)b * NQ + r] = pq1[(size_t)b * NQ + s];
      }
    }
  } else if (blk < 8 + 2048) {
    ec_gn_core<64, 32, 64, true>(blk - 8, c4q1, c40, nullptr,
                                 yminA, ymaxA, gst1, g1w, g1b, inv1,
                                 W2, idx1, yminB, ymaxB, gst2, NQ, N0);
  } else {
    int bq = (blk - (8 + 2048)) * 4 + (threadIdx.x >> 6);
    knn_body<16>(bq, threadIdx.x & 63, c4q1, c4q1, NQ, NQ, knnB);
  }
}

// ---------------------------------------------------------------------------
// ec3g (256 thr): layer-3 edgeconv with INLINE-GN f2 + in-wave ctrY3.
// ---------------------------------------------------------------------------
__global__ __launch_bounds__(256) void ec3g_kernel(
    const int* __restrict__ knnB,
    const float* __restrict__ yminB, const float* __restrict__ ymaxB,
    const float* __restrict__ gst2, const float* __restrict__ g2w,
    const float* __restrict__ g2b, float inv2,
    const float* __restrict__ W3,
    float* __restrict__ yminC, float* __restrict__ ymaxC, float* __restrict__ gst3) {
  ec_gn_core<16, 64, 64, false>(blockIdx.x, nullptr, nullptr, knnB,
                                yminB, ymaxB, gst2, g2w, g2b, inv2,
                                W3, nullptr, yminC, ymaxC, gst3, NQ, NQ);
}

// ---------------------------------------------------------------------------
// mega3g (256 thr): FUSED knn4+ec4 with INLINE-GN f3 + in-wave ctrY4.
// ---------------------------------------------------------------------------
__global__ __launch_bounds__(256) void mega3g_kernel(
    const float4* __restrict__ c4q1, const float4* __restrict__ c4q2,
    const float* __restrict__ yminC, const float* __restrict__ ymaxC,
    const float* __restrict__ gst3, const float* __restrict__ g3w,
    const float* __restrict__ g3b, float inv3,
    const int* __restrict__ idx2, const float* __restrict__ W4,
    float* __restrict__ yminD, float* __restrict__ ymaxD, float* __restrict__ gst4) {
  ec_gn_core<16, 64, 128, true>(blockIdx.x, c4q2, c4q1, nullptr,
                                yminC, ymaxC, gst3, g3w, g3b, inv3,
                                W4, idx2, yminD, ymaxD, gst4, NQ, NQ);
}

// ---------------------------------------------------------------------------
// pass B (gn_final fused): f = lrelu((sel - m)*gw*rs + gb) — final output.
// ---------------------------------------------------------------------------
template <int CO>
__global__ void gn_out_kernel(const float* __restrict__ ymin, const float* __restrict__ ymax,
                              const float* __restrict__ gstats, const float* __restrict__ gw,
                              const float* __restrict__ gb, float* __restrict__ fout,
                              int total, int Q, float inv_cnt) {
  int i = blockIdx.x * 256 + threadIdx.x;
  if (i >= total) return;
  constexpr int J = CO / 4;
  int o = i % CO; int bq = i / CO; int b = bq / Q;
  int g = o / J;
  float m  = gstats[b * 8 + g] * inv_cnt;
  float s2 = gstats[b * 8 + 4 + g] * inv_cnt;
  float rs = rsqrtf(s2 - m * m + 1e-5f);
  float sc = gw[o] * rs;
  float sel = (sc >= 0.f) ? ymax[i] : ymin[i];
  float v = (sel - m) * sc + gb[o];
  fout[i] = (v > 0.f) ? v : 0.2f * v;
}

// ---------------------------------------------------------------------------
extern "C" void kernel_launch(void* const* d_in, const int* in_sizes, int n_in,
                              void* d_out, int out_size, void* d_ws, size_t ws_size,
                              hipStream_t stream) {
  (void)in_sizes; (void)n_in; (void)out_size; (void)ws_size;
  const float* x    = (const float*)d_in[0];
  const float* W_in = (const float*)d_in[1];
  const float* b_in = (const float*)d_in[2];
  const float* W1   = (const float*)d_in[3];
  const float* g1w  = (const float*)d_in[4];
  const float* g1b  = (const float*)d_in[5];
  const float* W2   = (const float*)d_in[6];
  const float* g2w  = (const float*)d_in[7];
  const float* g2b  = (const float*)d_in[8];
  const float* W3   = (const float*)d_in[9];
  const float* g3w  = (const float*)d_in[10];
  const float* g3b  = (const float*)d_in[11];
  const float* W4   = (const float*)d_in[12];
  const float* g4w  = (const float*)d_in[13];
  const float* g4b  = (const float*)d_in[14];

  float* ws = (float*)d_ws;
  size_t o_c40   = 0;                                          // float4-aligned
  size_t o_nrm   = o_c40   + (size_t)B * N0 * 4;
  size_t o_pl    = o_nrm   + (size_t)B * N0 * 3;
  size_t o_f0    = o_pl    + (size_t)B * N0;
  size_t o_ctrY1 = o_f0    + (size_t)B * N0 * 8;               // 1M floats
  size_t o_yAmin = o_ctrY1 + (size_t)B * N0 * 32;              // 1M
  size_t o_yAmax = o_yAmin + (size_t)B * N0 * 32;              // 1M
  size_t o_yBmin = o_yAmax + (size_t)B * N0 * 32;              // 0.5M
  size_t o_yBmax = o_yBmin + (size_t)B * NQ * 64;
  size_t o_yCmin = o_yBmax + (size_t)B * NQ * 64;
  size_t o_yCmax = o_yCmin + (size_t)B * NQ * 64;
  size_t o_knnB  = o_yCmax + (size_t)B * NQ * 64;              // int region
  size_t o_gst   = o_knnB  + (size_t)B * NQ * KNB;
  size_t o_idx1  = o_gst   + 4 * B * 8;                        // int region
  size_t o_idx2  = o_idx1  + (size_t)B * NQ;                   // int region
  size_t o_c4q1  = o_idx2  + (size_t)B * NQ;                   // float4-aligned
  size_t o_c4q2  = o_c4q1  + (size_t)B * NQ * 4;               // float4-aligned
  size_t o_nq1   = o_c4q2  + (size_t)B * NQ * 4;
  size_t o_pq1   = o_nq1   + (size_t)B * NQ * 3;

  float4* c40   = (float4*)(ws + o_c40);
  float*  nrm   = ws + o_nrm;    float* pl    = ws + o_pl;
  float*  f0    = ws + o_f0;     float* ctrY1 = ws + o_ctrY1;
  float*  yAmin = ws + o_yAmin;  float* yAmax = ws + o_yAmax;
  float*  yBmin = ws + o_yBmin;  float* yBmax = ws + o_yBmax;
  float*  yCmin = ws + o_yCmin;  float* yCmax = ws + o_yCmax;
  // Layer-4 minmax aliases: ctrY1 (dead after mega1) and yAmin (dead after mega2).
  float*  yDmin = ctrY1;
  float*  yDmax = yAmin;
  int*    knnB  = (int*)(ws + o_knnB);
  float*  gst   = ws + o_gst;
  int*    idx1  = (int*)(ws + o_idx1);
  int*    idx2  = (int*)(ws + o_idx2);
  float4* c4q1  = (float4*)(ws + o_c4q1);
  float4* c4q2  = (float4*)(ws + o_c4q2);
  float*  nq1   = ws + o_nq1;    float* pq1   = ws + o_pq1;

  float* out  = (float*)d_out;
  float* cq2  = out;                                   // (B,NQ,3)
  float* fout = out + (size_t)B * NQ * 3;              // (B,NQ,128)
  float* nq2  = fout + (size_t)B * NQ * 128;           // (B,NQ,3)
  float* pq2  = nq2 + (size_t)B * NQ * 3;              // (B,NQ,1)

  const float inv1 = 1.0f / (4096.0f * 16.0f * 8.0f);
  const float inv2 = 1.0f / (1024.0f * 16.0f * 16.0f);
  const float inv3 = 1.0f / (1024.0f * 16.0f * 16.0f);
  const float inv4 = 1.0f / (1024.0f * 16.0f * 32.0f);

  hipMemsetAsync(gst, 0, 4 * B * 8 * sizeof(float), stream);

  // stage 0: prep (+ ctrY1)
  prep_kernel<<<(B * N0 + 255) / 256, 256, 0, stream>>>(x, W_in, b_in, W1,
                                                        c40, nrm, pl, f0, ctrY1);

  // mega1: fps1 || fused knn1+ec1   (deps: prep only)
  mega1_kernel<<<8 + 8192, 256, 0, stream>>>(c40, nrm, pl, f0, W1, ctrY1,
                                             idx1, c4q1, nq1, pq1,
                                             yAmin, yAmax, gst + 0);

  // mega2: 1-wave fps2 v11 || inline-gn fused knn2+ec2 || knn3   (deps: mega1)
  mega2_kernel<<<8 + 2048 + 2048, 256, 0, stream>>>(
      c40, c4q1, nq1, pq1, yAmin, yAmax, gst + 0, g1w, g1b, inv1,
      idx1, W2, yBmin, yBmax, gst + B * 8,
      idx2, c4q2, cq2, nq2, pq2, knnB);

  // layer 3: inline-gn f2 + in-wave ctrY3 (knn3 -> knnB from mega2)
  ec3g_kernel<<<B * NQ / 4, 256, 0, stream>>>(
      knnB, yBmin, yBmax, gst + B * 8, g2w, g2b, inv2, W3,
      yCmin, yCmax, gst + 2 * B * 8);

  // layer 4: fused knn4+ec4 with inline-gn f3 + in-wave ctrY4
  mega3g_kernel<<<B * NQ / 4, 256, 0, stream>>>(
      c4q1, c4q2, yCmin, yCmax, gst + 2 * B * 8, g3w, g3b, inv3,
      idx2, W4, yDmin, yDmax, gst + 3 * B * 8);

  // final gn -> fout
  gn_out_kernel<128><<<(B * NQ * 128 + 255) / 256, 256, 0, stream>>>(
      yDmin, yDmax, gst + 3 * B * 8, g4w, g4b, fout, B * NQ * 128, NQ, inv4);
}

// Round 13
// 1434.359 us; speedup vs baseline: 1.2944x; 1.2380x over previous
//
#include <hip/hip_runtime.h>
#include <cstdint>

static constexpr int B   = 8;
static constexpr int N0  = 4096;
static constexpr int NQ  = 1024;
static constexpr int KNB = 16;

// ---------------------------------------------------------------------------
// u64 wave max; result valid in LANE 63 only. No readlane/ballot — pure VALU.
// ---------------------------------------------------------------------------
__device__ __forceinline__ unsigned long long wave_max_u64_l63(unsigned long long k) {
#define STEPU_(ctrl)                                                                    \
  {                                                                                     \
    unsigned lo_ = (unsigned)k, hi_ = (unsigned)(k >> 32);                              \
    unsigned plo_ = (unsigned)__builtin_amdgcn_update_dpp((int)lo_, (int)lo_, ctrl,     \
                                                          0xf, 0xf, false);             \
    unsigned phi_ = (unsigned)__builtin_amdgcn_update_dpp((int)hi_, (int)hi_, ctrl,     \
                                                          0xf, 0xf, false);             \
    unsigned long long pk_ = ((unsigned long long)phi_ << 32) | plo_;                   \
    if (pk_ > k) k = pk_;                                                               \
  }
  STEPU_(0x111) STEPU_(0x112) STEPU_(0x114) STEPU_(0x118) STEPU_(0x142) STEPU_(0x143)
#undef STEPU_
  return k;
}

// ---------------------------------------------------------------------------
// gn inline formula — EXACT same expression as gn_out_kernel (bit-identical).
// ---------------------------------------------------------------------------
__device__ __forceinline__ float gnf(float mx, float mn, float scv, float mo, float gb) {
  float sel = (scv >= 0.f) ? mx : mn;
  float v = (sel - mo) * scv + gb;
  return (v > 0.f) ? v : 0.2f * v;
}

// ---------------------------------------------------------------------------
// prep: split x; write packed c4 = {x,y,z,|c|^2}, normal, plane, f0, AND
// ctrY1 (layer-1 center projection) — same fmaf order as the old ctry body.
// ---------------------------------------------------------------------------
__global__ void prep_kernel(const float* __restrict__ x,
                            const float* __restrict__ W_in,
                            const float* __restrict__ b_in,
                            const float* __restrict__ W1,
                            float4* __restrict__ c4, float* __restrict__ nrm,
                            float* __restrict__ pl, float* __restrict__ f0,
                            float* __restrict__ ctrY1) {
  int i = blockIdx.x * 256 + threadIdx.x;
  if (i >= B * N0) return;
  const float* xp = x + (size_t)i * 7;
  float cx = xp[0], cy = xp[1], cz = xp[2];
  // tie-sensitive (feeds kNN distance): exact fp32, ref association order
  float kk = __fadd_rn(__fadd_rn(__fmul_rn(cx, cx), __fmul_rn(cy, cy)), __fmul_rn(cz, cz));
  c4[i] = make_float4(cx, cy, cz, kk);
  nrm[i * 3 + 0] = xp[3]; nrm[i * 3 + 1] = xp[4]; nrm[i * 3 + 2] = xp[5];
  pl[i] = xp[6];
  float f[8];
#pragma unroll
  for (int o = 0; o < 8; o++) {
    f[o] = cx * W_in[o * 3 + 0] + cy * W_in[o * 3 + 1] + cz * W_in[o * 3 + 2] + b_in[o];
    f0[(size_t)i * 8 + o] = f[o];
  }
#pragma unroll
  for (int o = 0; o < 32; o++) {
    const float* wp = W1 + (size_t)o * 16 + 8;
    float acc = 0.f;
#pragma unroll
    for (int c = 0; c < 8; c++) acc = fmaf(f[c], wp[c], acc);
    ctrY1[(size_t)i * 32 + o] = acc;
  }
}

// ---------------------------------------------------------------------------
// kNN body: STREAMING INSERTION TOP-K (harness-verified). Wave per query.
// ---------------------------------------------------------------------------
template <int NC>
__device__ __forceinline__ void knn_body(int bq, int lane,
                                         const float4* __restrict__ q4,
                                         const float4* __restrict__ k4,
                                         int Q, int Nk, int* __restrict__ out) {
  int b = bq / Q;
  float4 q = q4[bq];
  const float4* kb = k4 + (size_t)b * Nk + lane;
  const float INF    = __int_as_float(0x7f800000);
  const float NEGINF = __int_as_float(0xff800000);
  float myd = INF;
  int   myi = 0;
  float kth = INF;
  const bool isl0 = (lane & 15) == 0;
  constexpr int G = (NC >= 8) ? 8 : NC;
  for (int c0 = 0; c0 < NC; c0 += G) {
    float dg[G];
#pragma unroll
    for (int u = 0; u < G; u++) {
      float4 kp = kb[(c0 + u) * 64];
      float dot = __fadd_rn(__fadd_rn(__fmul_rn(q.x, kp.x), __fmul_rn(q.y, kp.y)),
                            __fmul_rn(q.z, kp.z));
      dg[u] = __fadd_rn(__fsub_rn(q.w, __fmul_rn(2.0f, dot)), kp.w);
    }
#pragma unroll
    for (int u = 0; u < G; u++) {
      float d = dg[u];
      unsigned long long msk = __ballot(d < kth);
      while (msk) {
        int j = __builtin_ctzll(msk);
        float dv = __int_as_float(__builtin_amdgcn_readlane(__float_as_int(d), j));
        int   iv = (c0 + u) * 64 + j;
        bool gt = (myd > dv);
        float pd = __int_as_float(__builtin_amdgcn_update_dpp(
            0, __float_as_int(myd), 0x111, 0xf, 0xf, true));
        int   pi = __builtin_amdgcn_update_dpp(0, myi, 0x111, 0xf, 0xf, true);
        pd = isl0 ? NEGINF : pd;
        bool tp = (pd > dv);
        float nd = tp ? pd : dv;
        int   ni = tp ? pi : iv;
        myd = gt ? nd : myd;
        myi = gt ? ni : myi;
        kth = __int_as_float(__builtin_amdgcn_readlane(__float_as_int(myd), 15));
        msk = __ballot(d < kth);
        msk = (j < 63) ? (msk & (~0ull << (j + 1))) : 0ull;
      }
    }
  }
  if (lane < KNB) out[(size_t)bq * KNB + lane] = myi;
}

// ---------------------------------------------------------------------------
// FPS v5 (harness-verified): BLK=256 (4 waves), one block per batch.
// ---------------------------------------------------------------------------
template <int NPTS>
__device__ __forceinline__ void fps_body(const float4* __restrict__ cb, int* w) {
  constexpr int BLK = 256;
  constexpr int M = NPTS / BLK;
  constexpr int NW = BLK / 64;  // 4
  __shared__ __align__(16) float2 sxy[NPTS];
  __shared__ float szz[NPTS];
  __shared__ __align__(16) unsigned long long skey[2][NW];
  const int tid = threadIdx.x;
  const int wid = tid >> 6, lane = tid & 63;
  float cx[M], cy[M], cz[M], dist[M];
#pragma unroll
  for (int i = 0; i < M; i++) {
    float4 p = cb[tid * M + i];
    cx[i] = p.x; cy[i] = p.y; cz[i] = p.z;
    dist[i] = 3.4e38f;
    sxy[tid * M + i] = make_float2(p.x, p.y);
    szz[tid * M + i] = p.z;
  }
  w[0] = w[1] = w[2] = w[3] = 0;
  float4 p0 = cb[0];
  float px = p0.x, py = p0.y, pz = p0.z;
  __syncthreads();
  for (int t = 1; t < NQ; t++) {
    float bv = -1.f; int bi = 0;
#pragma unroll
    for (int i = 0; i < M; i++) {
      float dx = __fsub_rn(cx[i], px), dy = __fsub_rn(cy[i], py), dz = __fsub_rn(cz[i], pz);
      float d = __fadd_rn(__fadd_rn(__fmul_rn(dx, dx), __fmul_rn(dy, dy)), __fmul_rn(dz, dz));
      float dd = dist[i]; dd = (d < dd) ? d : dd; dist[i] = dd;
      if (dd > bv) { bv = dd; bi = tid * M + i; }
    }
    unsigned long long k =
        ((unsigned long long)__float_as_uint(bv) << 12) | (unsigned)(4095 - bi);
    k = wave_max_u64_l63(k);
    int p = t & 1;
    if (lane == 63) skey[p][wid] = k;
    __syncthreads();
    ulonglong2 ab = *(const ulonglong2*)&skey[p][0];
    ulonglong2 cd = *(const ulonglong2*)&skey[p][2];
    unsigned long long m0 = (ab.x > ab.y) ? ab.x : ab.y;
    unsigned long long m1 = (cd.x > cd.y) ? cd.x : cd.y;
    unsigned long long mk = (m0 > m1) ? m0 : m1;
    int win = 4095 - (int)(mk & 0xFFFull);
    float2 pxy = sxy[win];
    px = pxy.x; py = pxy.y; pz = szz[win];
    if (t == tid) w[0] = win;
    if (t == tid + 256) w[1] = win;
    if (t == tid + 512) w[2] = win;
    if (t == tid + 768) w[3] = win;
  }
}

// ---------------------------------------------------------------------------
// FUSED kNN + edge-conv body (layer 1; f0/ctrY1 materialized). Verbatim R8.
// ---------------------------------------------------------------------------
template <int NC, int CF, int CO>
__device__ __forceinline__ void knnec_body(
    int blkid, const float4* __restrict__ q4, const float4* __restrict__ k4,
    const float* __restrict__ fq, const float* __restrict__ fk,
    const float* __restrict__ Wfull, const float* __restrict__ ctrY,
    const int* __restrict__ ridx,
    float* __restrict__ ymin, float* __restrict__ ymax,
    float* __restrict__ gstats, int Q, int Nk) {
  constexpr int J = CO / 4;
  constexpr int SEC = J * CF + 8;
  __shared__ float Wl[4 * SEC];
  __shared__ float sstat[8];
  for (int t = threadIdx.x; t < CO * CF; t += 256) {
    int o = t / CF, c = t % CF;
    Wl[(o / J) * SEC + (o % J) * CF + c] = Wfull[(size_t)o * (2 * CF) + c];
  }
  if (threadIdx.x < 8) sstat[threadIdx.x] = 0.0f;
  __syncthreads();
  const int wid = threadIdx.x >> 6, lane = threadIdx.x & 63;
  const int bq = blkid * 4 + wid;
  const int b = bq / Q;
  // kNN phase
  float4 q = q4[bq];
  const float4* kb = k4 + (size_t)b * Nk + lane;
  const float INF    = __int_as_float(0x7f800000);
  const float NEGINF = __int_as_float(0xff800000);
  float myd = INF;
  int   myi = 0;
  float kth = INF;
  const bool isl0 = (lane & 15) == 0;
  constexpr int G = (NC >= 8) ? 8 : NC;
  for (int c0 = 0; c0 < NC; c0 += G) {
    float dg[G];
#pragma unroll
    for (int u = 0; u < G; u++) {
      float4 kp = kb[(c0 + u) * 64];
      float dot = __fadd_rn(__fadd_rn(__fmul_rn(q.x, kp.x), __fmul_rn(q.y, kp.y)),
                            __fmul_rn(q.z, kp.z));
      dg[u] = __fadd_rn(__fsub_rn(q.w, __fmul_rn(2.0f, dot)), kp.w);
    }
#pragma unroll
    for (int u = 0; u < G; u++) {
      float d = dg[u];
      unsigned long long msk = __ballot(d < kth);
      while (msk) {
        int j = __builtin_ctzll(msk);
        float dv = __int_as_float(__builtin_amdgcn_readlane(__float_as_int(d), j));
        int   iv = (c0 + u) * 64 + j;
        bool gt = (myd > dv);
        float pd = __int_as_float(__builtin_amdgcn_update_dpp(
            0, __float_as_int(myd), 0x111, 0xf, 0xf, true));
        int   pi = __builtin_amdgcn_update_dpp(0, myi, 0x111, 0xf, 0xf, true);
        pd = isl0 ? NEGINF : pd;
        bool tp = (pd > dv);
        float nd = tp ? pd : dv;
        int   nI = tp ? pi : iv;
        myd = gt ? nd : myd;
        myi = gt ? nI : myi;
        kth = __int_as_float(__builtin_amdgcn_readlane(__float_as_int(myd), 15));
        msk = __ballot(d < kth);
        msk = (j < 63) ? (msk & (~0ull << (j + 1))) : 0ull;
      }
    }
  }
  // edge-conv phase
  const int g = lane >> 4;
  const int ni = myi;
  const float* nbp = fk + (size_t)(b * Nk + ni) * CF;
  const float* cp = ridx ? fq + ((size_t)b * Nk + ridx[bq]) * CF
                         : fq + (size_t)bq * CF;
  float acc[J];
#pragma unroll
  for (int j = 0; j < J; j++) acc[j] = 0.0f;
  const float* wg = &Wl[g * SEC];
#pragma unroll
  for (int c = 0; c < CF; c += 4) {
    float4 nb4 = *(const float4*)(nbp + c);
    float4 c4  = *(const float4*)(cp + c);
    float e0 = nb4.x - c4.x, e1 = nb4.y - c4.y, e2 = nb4.z - c4.z, e3 = nb4.w - c4.w;
#pragma unroll
    for (int j = 0; j < J; j++) {
      float4 w4 = *(const float4*)(wg + j * CF + c);
      acc[j] = fmaf(e0, w4.x, acc[j]);
      acc[j] = fmaf(e1, w4.y, acc[j]);
      acc[j] = fmaf(e2, w4.z, acc[j]);
      acc[j] = fmaf(e3, w4.w, acc[j]);
    }
  }
  float s = 0.f, s2 = 0.f;
  const float* cyp = ctrY + (size_t)bq * CO + g * J;
#pragma unroll
  for (int j = 0; j < J; j++) {
    float y = acc[j] + cyp[j];
    acc[j] = y;
    s += y; s2 = fmaf(y, y, s2);
  }
  float mn[J];
#pragma unroll
  for (int j = 0; j < J; j++) mn[j] = acc[j];
#pragma unroll
  for (int m = 1; m < 16; m <<= 1) {
#pragma unroll
    for (int j = 0; j < J; j++) {
      float a = __shfl_xor(acc[j], m); if (a > acc[j]) acc[j] = a;
      float c2 = __shfl_xor(mn[j], m); if (c2 < mn[j]) mn[j] = c2;
    }
    s  += __shfl_xor(s, m);
    s2 += __shfl_xor(s2, m);
  }
  if ((lane & 15) == 0) {
    float* mnp = ymin + (size_t)bq * CO + g * J;
    float* mxp = ymax + (size_t)bq * CO + g * J;
#pragma unroll
    for (int j = 0; j < J; j++) { mnp[j] = mn[j]; mxp[j] = acc[j]; }
    atomicAdd(&sstat[g], s);
    atomicAdd(&sstat[4 + g], s2);
  }
  __syncthreads();
  if (threadIdx.x < 8) atomicAdd(&gstats[b * 8 + threadIdx.x], sstat[threadIdx.x]);
}

// ---------------------------------------------------------------------------
// INLINE-GN edge-conv core (layers 2-4). Previous-layer features are NOT
// materialized: each f-element is computed from (yminP,ymaxP,gstP,gwP,gbP)
// via gnf — the exact gn_out expression (bit-identical). The center row fc
// and this layer's ctrY row are computed per-wave in LDS (same fmaf order
// as the old ctry body). HAS_KNN: run the streaming top-K first (ni=myi);
// else ni comes from the knn[] array.
// ---------------------------------------------------------------------------
template <int NC, int CF, int CO, bool HAS_KNN>
__device__ __forceinline__ void ec_gn_core(
    int blkid, const float4* __restrict__ q4, const float4* __restrict__ k4,
    const int* __restrict__ knn,
    const float* __restrict__ yminP, const float* __restrict__ ymaxP,
    const float* __restrict__ gstP, const float* __restrict__ gwP,
    const float* __restrict__ gbP, float invP,
    const float* __restrict__ Wfull, const int* __restrict__ ridx,
    float* __restrict__ ymin, float* __restrict__ ymax,
    float* __restrict__ gstats, int Q, int Nk) {
  constexpr int J = CO / 4;
  constexpr int SEC = J * CF + 8;
  __shared__ float Wl[4 * SEC];
  __shared__ float sstat[8];
  __shared__ __align__(16) float t_scv[CF];
  __shared__ __align__(16) float t_mo[CF];
  __shared__ __align__(16) float t_gb[CF];
  __shared__ __align__(16) float wfc[4][CF];
  __shared__ float scy[4][CO];
  const int b = (blkid * 4) / Q;  // block-uniform (Q % 4 == 0)
  for (int t = threadIdx.x; t < CO * CF; t += 256) {
    int o = t / CF, c = t % CF;
    Wl[(o / J) * SEC + (o % J) * CF + c] = Wfull[(size_t)o * (2 * CF) + c];
  }
  if (threadIdx.x < CF) {
    int c = threadIdx.x;
    int gg = c / (CF / 4);
    float m  = gstP[b * 8 + gg] * invP;
    float s2 = gstP[b * 8 + 4 + gg] * invP;
    float rs = rsqrtf(s2 - m * m + 1e-5f);
    t_scv[c] = gwP[c] * rs;
    t_mo[c]  = m;
    t_gb[c]  = gbP[c];
  }
  if (threadIdx.x < 8) sstat[threadIdx.x] = 0.0f;
  __syncthreads();
  const int wid = threadIdx.x >> 6, lane = threadIdx.x & 63;
  const int bq = blkid * 4 + wid;
  // center f row (inline-gn), then this-layer ctrY row (in-wave dot)
  size_t cbase = (ridx ? ((size_t)b * Nk + ridx[bq]) : (size_t)bq) * CF;
  if (lane < CF)
    wfc[wid][lane] = gnf(ymaxP[cbase + lane], yminP[cbase + lane],
                         t_scv[lane], t_mo[lane], t_gb[lane]);
  for (int oo = lane; oo < CO; oo += 64) {
    const float* wp = Wfull + (size_t)oo * (2 * CF) + CF;
    float acc0 = 0.f;
#pragma unroll
    for (int c = 0; c < CF; c++) acc0 = fmaf(wfc[wid][c], wp[c], acc0);
    scy[wid][oo] = acc0;
  }
  // neighbor index
  int ni;
  if (HAS_KNN) {
    float4 q = q4[bq];
    const float4* kb = k4 + (size_t)b * Nk + lane;
    const float INF    = __int_as_float(0x7f800000);
    const float NEGINF = __int_as_float(0xff800000);
    float myd = INF;
    int   myi = 0;
    float kth = INF;
    const bool isl0 = (lane & 15) == 0;
    constexpr int G = (NC >= 8) ? 8 : NC;
    for (int c0 = 0; c0 < NC; c0 += G) {
      float dg[G];
#pragma unroll
      for (int u = 0; u < G; u++) {
        float4 kp = kb[(c0 + u) * 64];
        float dot = __fadd_rn(__fadd_rn(__fmul_rn(q.x, kp.x), __fmul_rn(q.y, kp.y)),
                              __fmul_rn(q.z, kp.z));
        dg[u] = __fadd_rn(__fsub_rn(q.w, __fmul_rn(2.0f, dot)), kp.w);
      }
#pragma unroll
      for (int u = 0; u < G; u++) {
        float d = dg[u];
        unsigned long long msk = __ballot(d < kth);
        while (msk) {
          int j = __builtin_ctzll(msk);
          float dv = __int_as_float(__builtin_amdgcn_readlane(__float_as_int(d), j));
          int   iv = (c0 + u) * 64 + j;
          bool gt = (myd > dv);
          float pd = __int_as_float(__builtin_amdgcn_update_dpp(
              0, __float_as_int(myd), 0x111, 0xf, 0xf, true));
          int   pi = __builtin_amdgcn_update_dpp(0, myi, 0x111, 0xf, 0xf, true);
          pd = isl0 ? NEGINF : pd;
          bool tp = (pd > dv);
          float nd = tp ? pd : dv;
          int   nI = tp ? pi : iv;
          myd = gt ? nd : myd;
          myi = gt ? nI : myi;
          kth = __int_as_float(__builtin_amdgcn_readlane(__float_as_int(myd), 15));
          msk = __ballot(d < kth);
          msk = (j < 63) ? (msk & (~0ull << (j + 1))) : 0ull;
        }
      }
    }
    ni = myi;
  } else {
    ni = knn[(size_t)bq * KNB + (lane & 15)];
  }
  // edge-conv phase with inline-gn neighbor loads
  const int g = lane >> 4;
  size_t nbase = ((size_t)b * Nk + ni) * CF;
  float acc[J];
#pragma unroll
  for (int j = 0; j < J; j++) acc[j] = 0.0f;
  const float* wg = &Wl[g * SEC];
#pragma unroll
  for (int c = 0; c < CF; c += 4) {
    float4 mx4 = *(const float4*)(ymaxP + nbase + c);
    float4 mn4 = *(const float4*)(yminP + nbase + c);
    float4 sc4 = *(const float4*)(&t_scv[c]);
    float4 mo4 = *(const float4*)(&t_mo[c]);
    float4 gb4 = *(const float4*)(&t_gb[c]);
    float4 c4  = *(const float4*)(&wfc[wid][c]);
    float e0 = gnf(mx4.x, mn4.x, sc4.x, mo4.x, gb4.x) - c4.x;
    float e1 = gnf(mx4.y, mn4.y, sc4.y, mo4.y, gb4.y) - c4.y;
    float e2 = gnf(mx4.z, mn4.z, sc4.z, mo4.z, gb4.z) - c4.z;
    float e3 = gnf(mx4.w, mn4.w, sc4.w, mo4.w, gb4.w) - c4.w;
#pragma unroll
    for (int j = 0; j < J; j++) {
      float4 w4 = *(const float4*)(wg + j * CF + c);
      acc[j] = fmaf(e0, w4.x, acc[j]);
      acc[j] = fmaf(e1, w4.y, acc[j]);
      acc[j] = fmaf(e2, w4.z, acc[j]);
      acc[j] = fmaf(e3, w4.w, acc[j]);
    }
  }
  float s = 0.f, s2 = 0.f;
#pragma unroll
  for (int j = 0; j < J; j++) {
    float y = acc[j] + scy[wid][g * J + j];
    acc[j] = y;
    s += y; s2 = fmaf(y, y, s2);
  }
  float mn[J];
#pragma unroll
  for (int j = 0; j < J; j++) mn[j] = acc[j];
#pragma unroll
  for (int m = 1; m < 16; m <<= 1) {
#pragma unroll
    for (int j = 0; j < J; j++) {
      float a = __shfl_xor(acc[j], m); if (a > acc[j]) acc[j] = a;
      float c2 = __shfl_xor(mn[j], m); if (c2 < mn[j]) mn[j] = c2;
    }
    s  += __shfl_xor(s, m);
    s2 += __shfl_xor(s2, m);
  }
  if ((lane & 15) == 0) {
    float* mnp = ymin + (size_t)bq * CO + g * J;
    float* mxp = ymax + (size_t)bq * CO + g * J;
#pragma unroll
    for (int j = 0; j < J; j++) { mnp[j] = mn[j]; mxp[j] = acc[j]; }
    atomicAdd(&sstat[g], s);
    atomicAdd(&sstat[4 + g], s2);
  }
  __syncthreads();
  if (threadIdx.x < 8) atomicAdd(&gstats[b * 8 + threadIdx.x], sstat[threadIdx.x]);
}

// ---------------------------------------------------------------------------
// mega1 (256 thr): blocks [0,8) fps1 (+ gather tail); rest FUSED knn1+ec1.
// ---------------------------------------------------------------------------
__global__ __launch_bounds__(256, 2) void mega1_kernel(
    const float4* __restrict__ c40, const float* __restrict__ nrm,
    const float* __restrict__ pl, const float* __restrict__ f0,
    const float* __restrict__ W1, const float* __restrict__ ctrY1,
    int* __restrict__ idx1,
    float4* __restrict__ c4q1, float* __restrict__ nq1, float* __restrict__ pq1,
    float* __restrict__ ymin, float* __restrict__ ymax, float* __restrict__ gst1) {
  int blk = blockIdx.x;
  if (blk < 8) {
    const int b = blk, tid = threadIdx.x;
    const float4* cb = c40 + (size_t)b * N0;
    int w[4];
    fps_body<N0>(cb, w);
    int* idxb = idx1 + (size_t)b * NQ;
#pragma unroll
    for (int u = 0; u < 4; u++) {
      int r = tid + u * 256;
      int s = (u == 0 && tid == 0) ? 0 : w[u];
      idxb[r] = s;
      c4q1[(size_t)b * NQ + r] = cb[s];
      const float* np = nrm + ((size_t)b * N0 + s) * 3;
      float* ndp = nq1 + ((size_t)b * NQ + r) * 3;
      ndp[0] = np[0]; ndp[1] = np[1]; ndp[2] = np[2];
      pq1[(size_t)b * NQ + r] = pl[(size_t)b * N0 + s];
    }
  } else {
    knnec_body<64, 8, 32>(blk - 8, c40, c40, f0, f0, W1, ctrY1, nullptr,
                          ymin, ymax, gst1, N0, N0);
  }
}

// ---------------------------------------------------------------------------
// mega2 (256 thr): [0,8) fps2 (+ gather tail); [8,8+2048) INLINE-GN fused
// knn2+ec2 (reads yA/gst1, computes f1 + ctrY2 on the fly); rest knn3->knnB.
// Starts immediately after mega1 (no gn1/ctry2 kernels).
// ---------------------------------------------------------------------------
__global__ __launch_bounds__(256, 2) void mega2_kernel(
    const float4* __restrict__ c40, const float4* __restrict__ c4q1,
    const float* __restrict__ nq1, const float* __restrict__ pq1,
    const float* __restrict__ yminA, const float* __restrict__ ymaxA,
    const float* __restrict__ gst1, const float* __restrict__ g1w,
    const float* __restrict__ g1b, float inv1,
    const int* __restrict__ idx1, const float* __restrict__ W2,
    float* __restrict__ yminB, float* __restrict__ ymaxB, float* __restrict__ gst2,
    int* __restrict__ idx2, float4* __restrict__ c4q2,
    float* __restrict__ cq2out, float* __restrict__ nq2out,
    float* __restrict__ pq2out, int* __restrict__ knnB) {
  int blk = blockIdx.x;
  if (blk < 8) {
    const int b = blk, tid = threadIdx.x;
    const float4* cqb = c4q1 + (size_t)b * NQ;
    int w[4];
    fps_body<NQ>(cqb, w);
    int* idxb = idx2 + (size_t)b * NQ;
#pragma unroll
    for (int u = 0; u < 4; u++) {
      int r = tid + u * 256;
      int s = (u == 0 && tid == 0) ? 0 : w[u];
      idxb[r] = s;
      float4 c = cqb[s];
      c4q2[(size_t)b * NQ + r] = c;
      float* cd = cq2out + ((size_t)b * NQ + r) * 3;
      cd[0] = c.x; cd[1] = c.y; cd[2] = c.z;
      const float* np = nq1 + ((size_t)b * NQ + s) * 3;
      float* ndp = nq2out + ((size_t)b * NQ + r) * 3;
      ndp[0] = np[0]; ndp[1] = np[1]; ndp[2] = np[2];
      pq2out[(size_t)b * NQ + r] = pq1[(size_t)b * NQ + s];
    }
  } else if (blk < 8 + 2048) {
    ec_gn_core<64, 32, 64, true>(blk - 8, c4q1, c40, nullptr,
                                 yminA, ymaxA, gst1, g1w, g1b, inv1,
                                 W2, idx1, yminB, ymaxB, gst2, NQ, N0);
  } else {
    int bq = (blk - (8 + 2048)) * 4 + (threadIdx.x >> 6);
    knn_body<16>(bq, threadIdx.x & 63, c4q1, c4q1, NQ, NQ, knnB);
  }
}

// ---------------------------------------------------------------------------
// ec3g (256 thr): layer-3 edgeconv with INLINE-GN f2 + in-wave ctrY3.
// Neighbors from knnB (knn3, computed in mega2); dense (no ridx).
// ---------------------------------------------------------------------------
__global__ __launch_bounds__(256) void ec3g_kernel(
    const int* __restrict__ knnB,
    const float* __restrict__ yminB, const float* __restrict__ ymaxB,
    const float* __restrict__ gst2, const float* __restrict__ g2w,
    const float* __restrict__ g2b, float inv2,
    const float* __restrict__ W3,
    float* __restrict__ yminC, float* __restrict__ ymaxC, float* __restrict__ gst3) {
  ec_gn_core<16, 64, 64, false>(blockIdx.x, nullptr, nullptr, knnB,
                                yminB, ymaxB, gst2, g2w, g2b, inv2,
                                W3, nullptr, yminC, ymaxC, gst3, NQ, NQ);
}

// ---------------------------------------------------------------------------
// mega3g (256 thr): FUSED knn4+ec4 with INLINE-GN f3 + in-wave ctrY4.
// ---------------------------------------------------------------------------
__global__ __launch_bounds__(256) void mega3g_kernel(
    const float4* __restrict__ c4q1, const float4* __restrict__ c4q2,
    const float* __restrict__ yminC, const float* __restrict__ ymaxC,
    const float* __restrict__ gst3, const float* __restrict__ g3w,
    const float* __restrict__ g3b, float inv3,
    const int* __restrict__ idx2, const float* __restrict__ W4,
    float* __restrict__ yminD, float* __restrict__ ymaxD, float* __restrict__ gst4) {
  ec_gn_core<16, 64, 128, true>(blockIdx.x, c4q2, c4q1, nullptr,
                                yminC, ymaxC, gst3, g3w, g3b, inv3,
                                W4, idx2, yminD, ymaxD, gst4, NQ, NQ);
}

// ---------------------------------------------------------------------------
// pass B (gn_final fused): f = lrelu((sel - m)*gw*rs + gb) — final output.
// ---------------------------------------------------------------------------
template <int CO>
__global__ void gn_out_kernel(const float* __restrict__ ymin, const float* __restrict__ ymax,
                              const float* __restrict__ gstats, const float* __restrict__ gw,
                              const float* __restrict__ gb, float* __restrict__ fout,
                              int total, int Q, float inv_cnt) {
  int i = blockIdx.x * 256 + threadIdx.x;
  if (i >= total) return;
  constexpr int J = CO / 4;
  int o = i % CO; int bq = i / CO; int b = bq / Q;
  int g = o / J;
  float m  = gstats[b * 8 + g] * inv_cnt;
  float s2 = gstats[b * 8 + 4 + g] * inv_cnt;
  float rs = rsqrtf(s2 - m * m + 1e-5f);
  float sc = gw[o] * rs;
  float sel = (sc >= 0.f) ? ymax[i] : ymin[i];
  float v = (sel - m) * sc + gb[o];
  fout[i] = (v > 0.f) ? v : 0.2f * v;
}

// ---------------------------------------------------------------------------
extern "C" void kernel_launch(void* const* d_in, const int* in_sizes, int n_in,
                              void* d_out, int out_size, void* d_ws, size_t ws_size,
                              hipStream_t stream) {
  (void)in_sizes; (void)n_in; (void)out_size; (void)ws_size;
  const float* x    = (const float*)d_in[0];
  const float* W_in = (const float*)d_in[1];
  const float* b_in = (const float*)d_in[2];
  const float* W1   = (const float*)d_in[3];
  const float* g1w  = (const float*)d_in[4];
  const float* g1b  = (const float*)d_in[5];
  const float* W2   = (const float*)d_in[6];
  const float* g2w  = (const float*)d_in[7];
  const float* g2b  = (const float*)d_in[8];
  const float* W3   = (const float*)d_in[9];
  const float* g3w  = (const float*)d_in[10];
  const float* g3b  = (const float*)d_in[11];
  const float* W4   = (const float*)d_in[12];
  const float* g4w  = (const float*)d_in[13];
  const float* g4b  = (const float*)d_in[14];

  float* ws = (float*)d_ws;
  size_t o_c40   = 0;                                          // float4-aligned
  size_t o_nrm   = o_c40   + (size_t)B * N0 * 4;
  size_t o_pl    = o_nrm   + (size_t)B * N0 * 3;
  size_t o_f0    = o_pl    + (size_t)B * N0;
  size_t o_ctrY1 = o_f0    + (size_t)B * N0 * 8;               // 1M floats
  size_t o_yAmin = o_ctrY1 + (size_t)B * N0 * 32;              // 1M
  size_t o_yAmax = o_yAmin + (size_t)B * N0 * 32;              // 1M
  size_t o_yBmin = o_yAmax + (size_t)B * N0 * 32;              // 0.5M
  size_t o_yBmax = o_yBmin + (size_t)B * NQ * 64;
  size_t o_yCmin = o_yBmax + (size_t)B * NQ * 64;
  size_t o_yCmax = o_yCmin + (size_t)B * NQ * 64;
  size_t o_knnB  = o_yCmax + (size_t)B * NQ * 64;              // int region
  size_t o_gst   = o_knnB  + (size_t)B * NQ * KNB;
  size_t o_idx1  = o_gst   + 4 * B * 8;                        // int region
  size_t o_idx2  = o_idx1  + (size_t)B * NQ;                   // int region
  size_t o_c4q1  = o_idx2  + (size_t)B * NQ;                   // float4-aligned
  size_t o_c4q2  = o_c4q1  + (size_t)B * NQ * 4;               // float4-aligned
  size_t o_nq1   = o_c4q2  + (size_t)B * NQ * 4;
  size_t o_pq1   = o_nq1   + (size_t)B * NQ * 3;

  float4* c40   = (float4*)(ws + o_c40);
  float*  nrm   = ws + o_nrm;    float* pl    = ws + o_pl;
  float*  f0    = ws + o_f0;     float* ctrY1 = ws + o_ctrY1;
  float*  yAmin = ws + o_yAmin;  float* yAmax = ws + o_yAmax;
  float*  yBmin = ws + o_yBmin;  float* yBmax = ws + o_yBmax;
  float*  yCmin = ws + o_yCmin;  float* yCmax = ws + o_yCmax;
  // Layer-4 minmax aliases: ctrY1 (dead after mega1) and yAmin (dead after mega2).
  float*  yDmin = ctrY1;
  float*  yDmax = yAmin;
  int*    knnB  = (int*)(ws + o_knnB);
  float*  gst   = ws + o_gst;
  int*    idx1  = (int*)(ws + o_idx1);
  int*    idx2  = (int*)(ws + o_idx2);
  float4* c4q1  = (float4*)(ws + o_c4q1);
  float4* c4q2  = (float4*)(ws + o_c4q2);
  float*  nq1   = ws + o_nq1;    float* pq1   = ws + o_pq1;

  float* out  = (float*)d_out;
  float* cq2  = out;                                   // (B,NQ,3)
  float* fout = out + (size_t)B * NQ * 3;              // (B,NQ,128)
  float* nq2  = fout + (size_t)B * NQ * 128;           // (B,NQ,3)
  float* pq2  = nq2 + (size_t)B * NQ * 3;              // (B,NQ,1)

  const float inv1 = 1.0f / (4096.0f * 16.0f * 8.0f);
  const float inv2 = 1.0f / (1024.0f * 16.0f * 16.0f);
  const float inv3 = 1.0f / (1024.0f * 16.0f * 16.0f);
  const float inv4 = 1.0f / (1024.0f * 16.0f * 32.0f);

  hipMemsetAsync(gst, 0, 4 * B * 8 * sizeof(float), stream);

  // stage 0: prep (+ ctrY1)
  prep_kernel<<<(B * N0 + 255) / 256, 256, 0, stream>>>(x, W_in, b_in, W1,
                                                        c40, nrm, pl, f0, ctrY1);

  // mega1: fps1 || fused knn1+ec1   (deps: prep only)
  mega1_kernel<<<8 + 8192, 256, 0, stream>>>(c40, nrm, pl, f0, W1, ctrY1,
                                             idx1, c4q1, nq1, pq1,
                                             yAmin, yAmax, gst + 0);

  // mega2: fps2 || inline-gn fused knn2+ec2 || knn3   (deps: mega1 only)
  mega2_kernel<<<8 + 2048 + 2048, 256, 0, stream>>>(
      c40, c4q1, nq1, pq1, yAmin, yAmax, gst + 0, g1w, g1b, inv1,
      idx1, W2, yBmin, yBmax, gst + B * 8,
      idx2, c4q2, cq2, nq2, pq2, knnB);

  // layer 3: inline-gn f2 + in-wave ctrY3 (knn3 -> knnB from mega2)
  ec3g_kernel<<<B * NQ / 4, 256, 0, stream>>>(
      knnB, yBmin, yBmax, gst + B * 8, g2w, g2b, inv2, W3,
      yCmin, yCmax, gst + 2 * B * 8);

  // layer 4: fused knn4+ec4 with inline-gn f3 + in-wave ctrY4
  mega3g_kernel<<<B * NQ / 4, 256, 0, stream>>>(
      c4q1, c4q2, yCmin, yCmax, gst + 2 * B * 8, g3w, g3b, inv3,
      idx2, W4, yDmin, yDmax, gst + 3 * B * 8);

  // final gn -> fout
  gn_out_kernel<128><<<(B * NQ * 128 + 255) / 256, 256, 0, stream>>>(
      yDmin, yDmax, gst + 3 * B * 8, g4w, g4b, fout, B * NQ * 128, NQ, inv4);
}